// Round 1
// 246.496 us; speedup vs baseline: 1.0342x; 1.0342x over previous
//
#include <hip/hip_runtime.h>
#include <hip/hip_bf16.h>

#define N_NODES 50000
#define N_EDGES 800000
#define N_GRAPHS 500
#define IN_DIM 128
#define HID 64
#define OUT_DIM 10
#define NB_BUCK ((N_NODES + 63) >> 6)  // 782 buckets of 64 nodes
#define NBLK 256                       // edge chunks (~3128 edges each) -> 1 block/CU
#define BLDT 256                       // build-kernel block size

// ---- bf16 helpers: exact expand on load, RNE on store ----
__device__ __forceinline__ float bf2f(unsigned short u) {
    return __uint_as_float(((unsigned)u) << 16);
}
__device__ __forceinline__ unsigned short f2bf(float f) {
    unsigned x = __float_as_uint(f);
    x += 0x7fffu + ((x >> 16) & 1u);  // round-to-nearest-even
    return (unsigned short)(x >> 16);
}
// expand 8 bf16 (uint4) and accumulate into 8 floats
__device__ __forceinline__ void acc8(float a[8], uint4 r) {
    a[0] += __uint_as_float(r.x << 16);
    a[1] += __uint_as_float(r.x & 0xffff0000u);
    a[2] += __uint_as_float(r.y << 16);
    a[3] += __uint_as_float(r.y & 0xffff0000u);
    a[4] += __uint_as_float(r.z << 16);
    a[5] += __uint_as_float(r.z & 0xffff0000u);
    a[6] += __uint_as_float(r.w << 16);
    a[7] += __uint_as_float(r.w & 0xffff0000u);
}

// ---------------- P1: per-chunk bucket histogram (LDS, int4 edge reads) ----------------
__global__ __launch_bounds__(BLDT) void p1_hist_kernel(const int* __restrict__ dst,
                                                       int* __restrict__ bhist, int e, int epb) {
    __shared__ int h[NB_BUCK];
    int tid = threadIdx.x;
    int blk = blockIdx.x;
    for (int i = tid; i < NB_BUCK; i += BLDT) h[i] = 0;
    __syncthreads();
    int e0 = blk * epb;
    int e1 = e0 + epb;
    if (e1 > e) e1 = e;
    int i = e0 + tid * 4;
    for (; i + 3 < e1; i += BLDT * 4) {
        int4 d4 = *(const int4*)&dst[i];
        atomicAdd(&h[d4.x >> 6], 1);
        atomicAdd(&h[d4.y >> 6], 1);
        atomicAdd(&h[d4.z >> 6], 1);
        atomicAdd(&h[d4.w >> 6], 1);
    }
    for (int k = i; k < e1 && k < i + 4; ++k) atomicAdd(&h[dst[k] >> 6], 1);
    __syncthreads();
    for (int j = tid; j < NB_BUCK; j += BLDT) bhist[blk * NB_BUCK + j] = h[j];
}

// ---- scanA: per bucket, scan NBLK chunk counts IN PLACE (bhist -> exclusive bases) + total ----
__global__ __launch_bounds__(NBLK) void scanA_kernel(int* __restrict__ bhist,
                                                     int* __restrict__ bsum) {
    __shared__ int s[NBLK];
    int b = blockIdx.x;
    int t = threadIdx.x;  // NBLK threads
    int c = bhist[t * NB_BUCK + b];
    s[t] = c;
    __syncthreads();
    for (int off = 1; off < NBLK; off <<= 1) {
        int x = (t >= off) ? s[t - off] : 0;
        __syncthreads();
        s[t] += x;
        __syncthreads();
    }
    bhist[t * NB_BUCK + b] = s[t] - c;  // in-place: exclusive prefix for chunk t
    if (t == NBLK - 1) bsum[b] = s[t];
}

// ---------------- P2: place edges into bucket-grouped pairs (int4 edge reads) ------
// Each block recomputes the bucket-total exclusive scan in LDS (removes the bscan
// kernel); block 0 publishes bstart for the downstream csr+linear kernel.
__global__ __launch_bounds__(BLDT) void p2_place_kernel(
    const int* __restrict__ src, const int* __restrict__ dst,
    const int* __restrict__ bsum, const int* __restrict__ base,
    unsigned* __restrict__ pairs, int* __restrict__ bstart, int e, int epb) {
    __shared__ int h[NB_BUCK];   // local rank counters
    __shared__ int sb[NB_BUCK];  // global segment base for this chunk
    __shared__ int ts[BLDT];     // per-thread totals for the scan
    int tid = threadIdx.x;
    int blk = blockIdx.x;
    // per-thread 4 contiguous bucket totals
    int i0 = tid << 2;
    int v0 = 0, v1 = 0, v2 = 0, v3 = 0;
    if (i0 < NB_BUCK) v0 = bsum[i0];
    if (i0 + 1 < NB_BUCK) v1 = bsum[i0 + 1];
    if (i0 + 2 < NB_BUCK) v2 = bsum[i0 + 2];
    if (i0 + 3 < NB_BUCK) v3 = bsum[i0 + 3];
    int tsum = v0 + v1 + v2 + v3;
    ts[tid] = tsum;
    for (int i = tid; i < NB_BUCK; i += BLDT) h[i] = 0;
    __syncthreads();
    for (int off = 1; off < BLDT; off <<= 1) {
        int x = (tid >= off) ? ts[tid - off] : 0;
        __syncthreads();
        ts[tid] += x;
        __syncthreads();
    }
    int excl = ts[tid] - tsum;  // exclusive over threads
    int s0 = excl;
    int s1 = s0 + v0;
    int s2 = s1 + v1;
    int s3 = s2 + v2;
    const int* bb = base + blk * NB_BUCK;
    if (i0 < NB_BUCK) sb[i0] = s0 + bb[i0];
    if (i0 + 1 < NB_BUCK) sb[i0 + 1] = s1 + bb[i0 + 1];
    if (i0 + 2 < NB_BUCK) sb[i0 + 2] = s2 + bb[i0 + 2];
    if (i0 + 3 < NB_BUCK) sb[i0 + 3] = s3 + bb[i0 + 3];
    if (blk == 0) {
        if (i0 < NB_BUCK) bstart[i0] = s0;
        if (i0 + 1 < NB_BUCK) bstart[i0 + 1] = s1;
        if (i0 + 2 < NB_BUCK) bstart[i0 + 2] = s2;
        if (i0 + 3 < NB_BUCK) bstart[i0 + 3] = s3;
        if (tid == 0) bstart[NB_BUCK] = e;
    }
    __syncthreads();
    int e0 = blk * epb;
    int e1 = e0 + epb;
    if (e1 > e) e1 = e;
    int i = e0 + tid * 4;
    for (; i + 3 < e1; i += BLDT * 4) {
        int4 d4 = *(const int4*)&dst[i];
        int4 s4 = *(const int4*)&src[i];
        int b0 = d4.x >> 6, b1 = d4.y >> 6, b2 = d4.z >> 6, b3 = d4.w >> 6;
        int r0 = atomicAdd(&h[b0], 1);
        int r1 = atomicAdd(&h[b1], 1);
        int r2 = atomicAdd(&h[b2], 1);
        int r3 = atomicAdd(&h[b3], 1);
        pairs[sb[b0] + r0] = ((unsigned)(d4.x & 63) << 16) | (unsigned)s4.x;
        pairs[sb[b1] + r1] = ((unsigned)(d4.y & 63) << 16) | (unsigned)s4.y;
        pairs[sb[b2] + r2] = ((unsigned)(d4.z & 63) << 16) | (unsigned)s4.z;
        pairs[sb[b3] + r3] = ((unsigned)(d4.w & 63) << 16) | (unsigned)s4.w;
    }
    for (int k = i; k < e1 && k < i + 4; ++k) {
        int d = dst[k];
        int b = d >> 6;
        int r = atomicAdd(&h[b], 1);
        pairs[sb[b] + r] = ((unsigned)(d & 63) << 16) | (unsigned)src[k];
    }
}

// ------- fused: per-bucket CSR build (rs, dinv, csr_src) + layer-1 linear on the
// ------- same 64 nodes (dinv consumed from LDS, no global round trip) -----------
__global__ __launch_bounds__(256) void csr_lin1_kernel(
    const unsigned* __restrict__ pairs, const int* __restrict__ bstart,
    int* __restrict__ rs, float* __restrict__ dinv, int* __restrict__ csr_src,
    const float* __restrict__ A, const float* __restrict__ W,
    unsigned short* __restrict__ C, int n) {
    const int K = IN_DIM;
    __shared__ float As[64][K + 4];
    __shared__ float Ws[K][64];
    __shared__ int lcnt[64];
    __shared__ int lcur[64];
    __shared__ float sdinv[64];
    int b = blockIdx.x;
    int tid = threadIdx.x;
    int beg = bstart[b], end = bstart[b + 1];
    if (tid < 64) lcnt[tid] = 0;
    __syncthreads();
    for (int i = beg + tid; i < end; i += 256) atomicAdd(&lcnt[pairs[i] >> 16], 1);
    __syncthreads();
    if (tid < 64) {  // wave 0: scan the 64 node counts
        int c = lcnt[tid];
        int v = c;
#pragma unroll
        for (int off = 1; off < 64; off <<= 1) {
            int t = __shfl_up(v, off);
            if (tid >= off) v += t;
        }
        int excl = v - c;
        int node = b * 64 + tid;
        float dv = rsqrtf((float)(c + 1));
        if (node <= n) {
            rs[node] = beg + excl;  // node==n lands on rs[N]=E (last bucket's tail)
            if (node < n) dinv[node] = dv;
        }
        sdinv[tid] = dv;
        lcur[tid] = beg + excl;
    }
    __syncthreads();
    for (int i = beg + tid; i < end; i += 256) {
        unsigned p = pairs[i];
        int slot = atomicAdd(&lcur[p >> 16], 1);
        csr_src[slot] = (int)(p & 0xffffu);
    }

    // ---- layer-1 linear for nodes [b*64, b*64+64) ----
    int block0 = b * 64;
    int rows = n - block0;
    if (rows > 64) rows = 64;

    const float* Abase = A + (size_t)block0 * K;
    int totalA4 = (rows * K) >> 2;
    for (int i4 = tid; i4 < totalA4; i4 += 256) {
        int i = i4 << 2;
        float4 v = *(const float4*)(Abase + i);
        *(float4*)&As[i / K][i % K] = v;
    }
    {
        const float4* Wv = (const float4*)W;
        float4* Wsv = (float4*)&Ws[0][0];
        for (int i = tid; i < K * 16; i += 256) Wsv[i] = Wv[i];
    }
    __syncthreads();

    int tx = tid & 15;
    int ty = tid >> 4;
    float acc[4][4] = {};
#pragma unroll 2
    for (int k = 0; k < K; k += 4) {
        float4 a[4];
#pragma unroll
        for (int i = 0; i < 4; ++i) a[i] = *(const float4*)&As[ty * 4 + i][k];
        float4 w[4];
#pragma unroll
        for (int kk = 0; kk < 4; ++kk) w[kk] = *(const float4*)&Ws[k + kk][tx * 4];
#pragma unroll
        for (int i = 0; i < 4; ++i) {
            float av[4] = {a[i].x, a[i].y, a[i].z, a[i].w};
#pragma unroll
            for (int kk = 0; kk < 4; ++kk) {
                acc[i][0] += av[kk] * w[kk].x;
                acc[i][1] += av[kk] * w[kk].y;
                acc[i][2] += av[kk] * w[kk].z;
                acc[i][3] += av[kk] * w[kk].w;
            }
        }
    }

#pragma unroll
    for (int i = 0; i < 4; ++i) {
        int r = ty * 4 + i;
        if (r < rows) {
            float s = sdinv[r];
            ushort4 v;
            v.x = f2bf(acc[i][0] * s);
            v.y = f2bf(acc[i][1] * s);
            v.z = f2bf(acc[i][2] * s);
            v.w = f2bf(acc[i][3] * s);
            *(ushort4*)&C[(size_t)(block0 + r) * 64 + tx * 4] = v;
        }
    }
}

// ---------------- layers-2/3 linear: bf16 A (K=64) -> bf16 hs (+ dinv pre-scale) --------------
__global__ __launch_bounds__(256) void linear_bf_kernel(
    const unsigned short* __restrict__ A, const float* __restrict__ W,
    const float* __restrict__ dinv, unsigned short* __restrict__ C, int n) {
    const int K = HID;
    __shared__ float As[64][K + 4];
    __shared__ float Ws[K][64];
    int tid = threadIdx.x;
    int tx = tid & 15;
    int ty = tid >> 4;
    int block0 = blockIdx.x * 64;
    int rows = n - block0;
    if (rows > 64) rows = 64;

    const unsigned short* Abase = A + (size_t)block0 * K;
    int total8 = rows * 8;  // 16B (8 bf16) units
    for (int u = tid; u < total8; u += 256) {
        int r = u >> 3;
        int c8 = (u & 7) << 3;
        uint4 raw = *(const uint4*)(Abase + (size_t)r * K + c8);
        float4 a0, a1;
        a0.x = __uint_as_float(raw.x << 16);
        a0.y = __uint_as_float(raw.x & 0xffff0000u);
        a0.z = __uint_as_float(raw.y << 16);
        a0.w = __uint_as_float(raw.y & 0xffff0000u);
        a1.x = __uint_as_float(raw.z << 16);
        a1.y = __uint_as_float(raw.z & 0xffff0000u);
        a1.z = __uint_as_float(raw.w << 16);
        a1.w = __uint_as_float(raw.w & 0xffff0000u);
        *(float4*)&As[r][c8] = a0;
        *(float4*)&As[r][c8 + 4] = a1;
    }
    {
        const float4* Wv = (const float4*)W;
        float4* Wsv = (float4*)&Ws[0][0];
        for (int i = tid; i < K * 16; i += 256) Wsv[i] = Wv[i];
    }
    __syncthreads();

    float acc[4][4] = {};
#pragma unroll 2
    for (int k = 0; k < K; k += 4) {
        float4 a[4];
#pragma unroll
        for (int i = 0; i < 4; ++i) a[i] = *(const float4*)&As[ty * 4 + i][k];
        float4 w[4];
#pragma unroll
        for (int kk = 0; kk < 4; ++kk) w[kk] = *(const float4*)&Ws[k + kk][tx * 4];
#pragma unroll
        for (int i = 0; i < 4; ++i) {
            float av[4] = {a[i].x, a[i].y, a[i].z, a[i].w};
#pragma unroll
            for (int kk = 0; kk < 4; ++kk) {
                acc[i][0] += av[kk] * w[kk].x;
                acc[i][1] += av[kk] * w[kk].y;
                acc[i][2] += av[kk] * w[kk].z;
                acc[i][3] += av[kk] * w[kk].w;
            }
        }
    }

#pragma unroll
    for (int i = 0; i < 4; ++i) {
        int r = ty * 4 + i;
        if (r < rows) {
            float s = dinv[block0 + r];
            ushort4 v;
            v.x = f2bf(acc[i][0] * s);
            v.y = f2bf(acc[i][1] * s);
            v.z = f2bf(acc[i][2] * s);
            v.w = f2bf(acc[i][3] * s);
            *(ushort4*)&C[(size_t)(block0 + r) * 64 + tx * 4] = v;
        }
    }
}

// ------- per-node bf16 gather: 16B/lane loads, 8 lanes/row, 8 edge groups -------------
__global__ __launch_bounds__(256) void gather_kernel(
    const unsigned short* __restrict__ hs, const int* __restrict__ rs,
    const int* __restrict__ csr_src, const float* __restrict__ dinv,
    const float* __restrict__ bias, unsigned short* __restrict__ outp, int n) {
    int wave = threadIdx.x >> 6;
    int node = blockIdx.x * 4 + wave;
    if (node >= n) return;
    int lane = threadIdx.x & 63;
    int eg = lane >> 3;        // edge group 0..7
    int f8 = (lane & 7) << 3;  // feature octet base
    int beg = rs[node], end = rs[node + 1];
    int len = end - beg;
    int q = (len + 7) >> 3;    // per-group quota (contiguous eighth)
    int mb = beg + eg * q;
    int me = mb + q;
    if (me > end) me = end;
    float a[8] = {0.f, 0.f, 0.f, 0.f, 0.f, 0.f, 0.f, 0.f};
    if (eg == 0) {  // self-loop (pre-scaled)
        uint4 r = *(const uint4*)&hs[(size_t)node * 64 + f8];
        acc8(a, r);
    }
    int j = mb;
    for (; j + 3 < me; j += 4) {  // 4 rows in flight
        int s0 = csr_src[j];
        int s1 = csr_src[j + 1];
        int s2 = csr_src[j + 2];
        int s3 = csr_src[j + 3];
        uint4 r0 = *(const uint4*)&hs[(size_t)s0 * 64 + f8];
        uint4 r1 = *(const uint4*)&hs[(size_t)s1 * 64 + f8];
        uint4 r2 = *(const uint4*)&hs[(size_t)s2 * 64 + f8];
        uint4 r3 = *(const uint4*)&hs[(size_t)s3 * 64 + f8];
        acc8(a, r0);
        acc8(a, r1);
        acc8(a, r2);
        acc8(a, r3);
    }
    if (j + 1 < me) {  // 2 rows in flight
        int s0 = csr_src[j];
        int s1 = csr_src[j + 1];
        uint4 r0 = *(const uint4*)&hs[(size_t)s0 * 64 + f8];
        uint4 r1 = *(const uint4*)&hs[(size_t)s1 * 64 + f8];
        acc8(a, r0);
        acc8(a, r1);
        j += 2;
    }
    if (j < me) {
        int s0 = csr_src[j];
        uint4 r0 = *(const uint4*)&hs[(size_t)s0 * 64 + f8];
        acc8(a, r0);
    }
    // merge the 8 edge groups: butterfly over lane bits 3,4,5
#pragma unroll
    for (int k = 0; k < 8; ++k) a[k] += __shfl_xor(a[k], 8);
#pragma unroll
    for (int k = 0; k < 8; ++k) a[k] += __shfl_xor(a[k], 16);
#pragma unroll
    for (int k = 0; k < 8; ++k) a[k] += __shfl_xor(a[k], 32);
    if (eg == 0) {
        float s = dinv[node];
        float4 b0 = *(const float4*)&bias[f8];
        float4 b1 = *(const float4*)&bias[f8 + 4];
        float v0 = fmaxf(a[0] * s + b0.x, 0.f);
        float v1 = fmaxf(a[1] * s + b0.y, 0.f);
        float v2 = fmaxf(a[2] * s + b0.z, 0.f);
        float v3 = fmaxf(a[3] * s + b0.w, 0.f);
        float v4 = fmaxf(a[4] * s + b1.x, 0.f);
        float v5 = fmaxf(a[5] * s + b1.y, 0.f);
        float v6 = fmaxf(a[6] * s + b1.z, 0.f);
        float v7 = fmaxf(a[7] * s + b1.w, 0.f);
        uint4 o;
        o.x = (unsigned)f2bf(v0) | ((unsigned)f2bf(v1) << 16);
        o.y = (unsigned)f2bf(v2) | ((unsigned)f2bf(v3) << 16);
        o.z = (unsigned)f2bf(v4) | ((unsigned)f2bf(v5) << 16);
        o.w = (unsigned)f2bf(v6) | ((unsigned)f2bf(v7) << 16);
        *(uint4*)&outp[(size_t)node * 64 + f8] = o;
    }
}

// ---------------- fused segmented mean-pool + MLP head (4-wave row-sum, bf16 in) -------------
__device__ __forceinline__ int lower_bound_dev(const int* __restrict__ a, int n, int v) {
    int lo = 0, hi = n;
    while (lo < hi) {
        int m = (lo + hi) >> 1;
        if (a[m] < v) lo = m + 1; else hi = m;
    }
    return lo;
}

__global__ __launch_bounds__(256) void pool_head_kernel(
    const unsigned short* __restrict__ h, const int* __restrict__ batch,
    const float* __restrict__ W1, const float* __restrict__ b1,
    const float* __restrict__ W2, const float* __restrict__ b2,
    float* __restrict__ out, int nNodes, int nGraphs) {
    __shared__ float psum[4][64];
    __shared__ float p[64];
    __shared__ float t64[64];
    int g = blockIdx.x;
    int tid = threadIdx.x;
    int f = tid & 63;
    int q = tid >> 6;  // wave id 0..3
    int lo = lower_bound_dev(batch, nNodes, g);
    int hi = lower_bound_dev(batch, nNodes, g + 1);
    float sum = 0.0f;
    for (int i = lo + q; i < hi; i += 4) sum += bf2f(h[(size_t)i * 64 + f]);
    psum[q][f] = sum;
    __syncthreads();
    if (tid < 64) {  // wave 0 only; intra-wave lockstep below
        float s = psum[0][f] + psum[1][f] + psum[2][f] + psum[3][f];
        float inv = 1.0f / fmaxf((float)(hi - lo), 1.0f);
        p[f] = s * inv;
        float acc = b1[f];
#pragma unroll
        for (int k = 0; k < 64; ++k) acc += p[k] * W1[k * 64 + f];
        t64[f] = fmaxf(acc, 0.0f);
        if (f < OUT_DIM) {
            float acc2 = b2[f];
#pragma unroll
            for (int k = 0; k < 64; ++k) acc2 += t64[k] * W2[k * OUT_DIM + f];
            out[g * OUT_DIM + f] = acc2;
        }
        if (g == 0 && f == 0) out[nGraphs * OUT_DIM] = 0.0f;  // trailing scalar output
    }
}

extern "C" void kernel_launch(void* const* d_in, const int* in_sizes, int n_in,
                              void* d_out, int out_size, void* d_ws, size_t ws_size,
                              hipStream_t stream) {
    const float* x      = (const float*)d_in[0];
    const int*   eidx   = (const int*)d_in[1];
    const int*   batch  = (const int*)d_in[2];
    const float* W1     = (const float*)d_in[3];
    const float* b1     = (const float*)d_in[4];
    const float* W2     = (const float*)d_in[5];
    const float* b2     = (const float*)d_in[6];
    const float* W3     = (const float*)d_in[7];
    const float* b3     = (const float*)d_in[8];
    const float* lin_W1 = (const float*)d_in[9];
    const float* lin_b1 = (const float*)d_in[10];
    const float* lin_W2 = (const float*)d_in[11];
    const float* lin_b2 = (const float*)d_in[12];
    float* out = (float*)d_out;

    const int E = in_sizes[1] / 2;
    const int N = N_NODES;
    const int NF = N * HID;
    int epb = (E + NBLK - 1) / NBLK;
    epb = (epb + 7) & ~7;  // multiple of 8 -> chunk bases stay 16B-aligned for int4 reads

    const int* src = eidx;
    const int* dst = eidx + E;

    // workspace layout
    unsigned short* buf1 = (unsigned short*)d_ws;  // hs bf16 [N,64]
    unsigned short* buf2 = buf1 + NF;              // h  bf16 [N,64]
    float* dinv = (float*)(buf2 + NF);             // [N]
    int* bhist  = (int*)(dinv + N);                // [NBLK * NB_BUCK] (in-place counts->bases)
    int* bsum   = bhist + NBLK * NB_BUCK;          // [NB_BUCK]
    int* bstart = bsum + NB_BUCK;                  // [NB_BUCK+1]
    int* rs     = bstart + NB_BUCK + 1;            // [N+1]
    int* csr_src = rs + N + 1;                     // [E]
    unsigned* pairs = (unsigned*)(csr_src + E);    // [E]

    const int TILES = (N + 63) / 64;  // 782 (== NB_BUCK)
    const int GBLK = (N + 3) / 4;     // 12500

    // ---- atomic-free edge build (bscan folded into p2; csr build fused with linear1) ----
    p1_hist_kernel<<<NBLK, BLDT, 0, stream>>>(dst, bhist, E, epb);
    scanA_kernel<<<NB_BUCK, NBLK, 0, stream>>>(bhist, bsum);
    p2_place_kernel<<<NBLK, BLDT, 0, stream>>>(src, dst, bsum, bhist, pairs, bstart, E, epb);

    // ---- layer 1 (fused csr_scatter + linear) ----
    csr_lin1_kernel<<<TILES, 256, 0, stream>>>(pairs, bstart, rs, dinv, csr_src,
                                               x, W1, buf1, N);
    gather_kernel<<<GBLK, 256, 0, stream>>>(buf1, rs, csr_src, dinv, b1, buf2, N);

    // ---- layer 2 ----
    linear_bf_kernel<<<TILES, 256, 0, stream>>>(buf2, W2, dinv, buf1, N);
    gather_kernel<<<GBLK, 256, 0, stream>>>(buf1, rs, csr_src, dinv, b2, buf2, N);

    // ---- layer 3 ----
    linear_bf_kernel<<<TILES, 256, 0, stream>>>(buf2, W3, dinv, buf1, N);
    gather_kernel<<<GBLK, 256, 0, stream>>>(buf1, rs, csr_src, dinv, b3, buf2, N);

    // ---- fused pool + head ----
    pool_head_kernel<<<N_GRAPHS, 256, 0, stream>>>(buf2, batch, lin_W1, lin_b1, lin_W2, lin_b2,
                                                   out, N, N_GRAPHS);
}

// Round 2
// 244.801 us; speedup vs baseline: 1.0414x; 1.0069x over previous
//
#include <hip/hip_runtime.h>
#include <hip/hip_bf16.h>

#define N_NODES 50000
#define N_EDGES 800000
#define N_GRAPHS 500
#define IN_DIM 128
#define HID 64
#define OUT_DIM 10
#define NB_BUCK ((N_NODES + 63) >> 6)  // 782 buckets of 64 nodes
#define NBLK 256                       // edge chunks (~3128 edges each) -> 1 block/CU
#define BLDT 1024                      // build-kernel block size: 16 waves/CU for latency hiding

// ---- bf16 helpers: exact expand on load, RNE on store ----
__device__ __forceinline__ float bf2f(unsigned short u) {
    return __uint_as_float(((unsigned)u) << 16);
}
__device__ __forceinline__ unsigned short f2bf(float f) {
    unsigned x = __float_as_uint(f);
    x += 0x7fffu + ((x >> 16) & 1u);  // round-to-nearest-even
    return (unsigned short)(x >> 16);
}
// expand 8 bf16 (uint4) and accumulate into 8 floats
__device__ __forceinline__ void acc8(float a[8], uint4 r) {
    a[0] += __uint_as_float(r.x << 16);
    a[1] += __uint_as_float(r.x & 0xffff0000u);
    a[2] += __uint_as_float(r.y << 16);
    a[3] += __uint_as_float(r.y & 0xffff0000u);
    a[4] += __uint_as_float(r.z << 16);
    a[5] += __uint_as_float(r.z & 0xffff0000u);
    a[6] += __uint_as_float(r.w << 16);
    a[7] += __uint_as_float(r.w & 0xffff0000u);
}

// ---------------- P1: per-chunk bucket histogram (LDS, int4 edge reads) ----------------
__global__ __launch_bounds__(BLDT) void p1_hist_kernel(const int* __restrict__ dst,
                                                       int* __restrict__ bhist, int e, int epb) {
    __shared__ int h[NB_BUCK];
    int tid = threadIdx.x;
    int blk = blockIdx.x;
    for (int i = tid; i < NB_BUCK; i += BLDT) h[i] = 0;
    __syncthreads();
    int e0 = blk * epb;
    int e1 = e0 + epb;
    if (e1 > e) e1 = e;
    int i = e0 + tid * 4;
    for (; i + 3 < e1; i += BLDT * 4) {
        int4 d4 = *(const int4*)&dst[i];
        atomicAdd(&h[d4.x >> 6], 1);
        atomicAdd(&h[d4.y >> 6], 1);
        atomicAdd(&h[d4.z >> 6], 1);
        atomicAdd(&h[d4.w >> 6], 1);
    }
    for (int k = i; k < e1 && k < i + 4; ++k) atomicAdd(&h[dst[k] >> 6], 1);
    __syncthreads();
    for (int j = tid; j < NB_BUCK; j += BLDT) bhist[blk * NB_BUCK + j] = h[j];
}

// ---- scanA: per bucket, scan NBLK chunk counts IN PLACE (bhist -> exclusive bases) + total ----
__global__ __launch_bounds__(NBLK) void scanA_kernel(int* __restrict__ bhist,
                                                     int* __restrict__ bsum) {
    __shared__ int s[NBLK];
    int b = blockIdx.x;
    int t = threadIdx.x;  // NBLK threads
    int c = bhist[t * NB_BUCK + b];
    s[t] = c;
    __syncthreads();
    for (int off = 1; off < NBLK; off <<= 1) {
        int x = (t >= off) ? s[t - off] : 0;
        __syncthreads();
        s[t] += x;
        __syncthreads();
    }
    bhist[t * NB_BUCK + b] = s[t] - c;  // in-place: exclusive prefix for chunk t
    if (t == NBLK - 1) bsum[b] = s[t];
}

// ---------------- P2: place edges into bucket-grouped pairs (int4 edge reads) ------
// Each block recomputes the bucket-total exclusive scan in LDS (removes the bscan
// kernel); block 0 publishes bstart for the downstream csr+linear kernel.
__global__ __launch_bounds__(BLDT) void p2_place_kernel(
    const int* __restrict__ src, const int* __restrict__ dst,
    const int* __restrict__ bsum, const int* __restrict__ base,
    unsigned* __restrict__ pairs, int* __restrict__ bstart, int e, int epb) {
    __shared__ int h[NB_BUCK];   // local rank counters
    __shared__ int sb[NB_BUCK];  // global segment base for this chunk
    __shared__ int ts[BLDT];     // per-thread totals for the scan
    int tid = threadIdx.x;
    int blk = blockIdx.x;
    // per-thread 4 contiguous bucket totals
    int i0 = tid << 2;
    int v0 = 0, v1 = 0, v2 = 0, v3 = 0;
    if (i0 < NB_BUCK) v0 = bsum[i0];
    if (i0 + 1 < NB_BUCK) v1 = bsum[i0 + 1];
    if (i0 + 2 < NB_BUCK) v2 = bsum[i0 + 2];
    if (i0 + 3 < NB_BUCK) v3 = bsum[i0 + 3];
    int tsum = v0 + v1 + v2 + v3;
    ts[tid] = tsum;
    for (int i = tid; i < NB_BUCK; i += BLDT) h[i] = 0;
    __syncthreads();
    for (int off = 1; off < BLDT; off <<= 1) {
        int x = (tid >= off) ? ts[tid - off] : 0;
        __syncthreads();
        ts[tid] += x;
        __syncthreads();
    }
    int excl = ts[tid] - tsum;  // exclusive over threads
    int s0 = excl;
    int s1 = s0 + v0;
    int s2 = s1 + v1;
    int s3 = s2 + v2;
    const int* bb = base + blk * NB_BUCK;
    if (i0 < NB_BUCK) sb[i0] = s0 + bb[i0];
    if (i0 + 1 < NB_BUCK) sb[i0 + 1] = s1 + bb[i0 + 1];
    if (i0 + 2 < NB_BUCK) sb[i0 + 2] = s2 + bb[i0 + 2];
    if (i0 + 3 < NB_BUCK) sb[i0 + 3] = s3 + bb[i0 + 3];
    if (blk == 0) {
        if (i0 < NB_BUCK) bstart[i0] = s0;
        if (i0 + 1 < NB_BUCK) bstart[i0 + 1] = s1;
        if (i0 + 2 < NB_BUCK) bstart[i0 + 2] = s2;
        if (i0 + 3 < NB_BUCK) bstart[i0 + 3] = s3;
        if (tid == 0) bstart[NB_BUCK] = e;
    }
    __syncthreads();
    int e0 = blk * epb;
    int e1 = e0 + epb;
    if (e1 > e) e1 = e;
    int i = e0 + tid * 4;
    for (; i + 3 < e1; i += BLDT * 4) {
        int4 d4 = *(const int4*)&dst[i];
        int4 s4 = *(const int4*)&src[i];
        int b0 = d4.x >> 6, b1 = d4.y >> 6, b2 = d4.z >> 6, b3 = d4.w >> 6;
        int r0 = atomicAdd(&h[b0], 1);
        int r1 = atomicAdd(&h[b1], 1);
        int r2 = atomicAdd(&h[b2], 1);
        int r3 = atomicAdd(&h[b3], 1);
        pairs[sb[b0] + r0] = ((unsigned)(d4.x & 63) << 16) | (unsigned)s4.x;
        pairs[sb[b1] + r1] = ((unsigned)(d4.y & 63) << 16) | (unsigned)s4.y;
        pairs[sb[b2] + r2] = ((unsigned)(d4.z & 63) << 16) | (unsigned)s4.z;
        pairs[sb[b3] + r3] = ((unsigned)(d4.w & 63) << 16) | (unsigned)s4.w;
    }
    for (int k = i; k < e1 && k < i + 4; ++k) {
        int d = dst[k];
        int b = d >> 6;
        int r = atomicAdd(&h[b], 1);
        pairs[sb[b] + r] = ((unsigned)(d & 63) << 16) | (unsigned)src[k];
    }
}

// ------- fused: per-bucket CSR build (rs, dinv, csr_src) + layer-1 linear on the
// ------- same 64 nodes (dinv consumed from LDS, no global round trip) -----------
__global__ __launch_bounds__(256) void csr_lin1_kernel(
    const unsigned* __restrict__ pairs, const int* __restrict__ bstart,
    int* __restrict__ rs, float* __restrict__ dinv, int* __restrict__ csr_src,
    const float* __restrict__ A, const float* __restrict__ W,
    unsigned short* __restrict__ C, int n) {
    const int K = IN_DIM;
    __shared__ float As[64][K + 4];
    __shared__ float Ws[K][64];
    __shared__ int lcnt[64];
    __shared__ int lcur[64];
    __shared__ float sdinv[64];
    int b = blockIdx.x;
    int tid = threadIdx.x;
    int beg = bstart[b], end = bstart[b + 1];
    if (tid < 64) lcnt[tid] = 0;
    __syncthreads();
    for (int i = beg + tid; i < end; i += 256) atomicAdd(&lcnt[pairs[i] >> 16], 1);
    __syncthreads();
    if (tid < 64) {  // wave 0: scan the 64 node counts
        int c = lcnt[tid];
        int v = c;
#pragma unroll
        for (int off = 1; off < 64; off <<= 1) {
            int t = __shfl_up(v, off);
            if (tid >= off) v += t;
        }
        int excl = v - c;
        int node = b * 64 + tid;
        float dv = rsqrtf((float)(c + 1));
        if (node <= n) {
            rs[node] = beg + excl;  // node==n lands on rs[N]=E (last bucket's tail)
            if (node < n) dinv[node] = dv;
        }
        sdinv[tid] = dv;
        lcur[tid] = beg + excl;
    }
    __syncthreads();
    for (int i = beg + tid; i < end; i += 256) {
        unsigned p = pairs[i];
        int slot = atomicAdd(&lcur[p >> 16], 1);
        csr_src[slot] = (int)(p & 0xffffu);
    }

    // ---- layer-1 linear for nodes [b*64, b*64+64) ----
    int block0 = b * 64;
    int rows = n - block0;
    if (rows > 64) rows = 64;

    const float* Abase = A + (size_t)block0 * K;
    int totalA4 = (rows * K) >> 2;
    for (int i4 = tid; i4 < totalA4; i4 += 256) {
        int i = i4 << 2;
        float4 v = *(const float4*)(Abase + i);
        *(float4*)&As[i / K][i % K] = v;
    }
    {
        const float4* Wv = (const float4*)W;
        float4* Wsv = (float4*)&Ws[0][0];
        for (int i = tid; i < K * 16; i += 256) Wsv[i] = Wv[i];
    }
    __syncthreads();

    int tx = tid & 15;
    int ty = tid >> 4;
    float acc[4][4] = {};
#pragma unroll 2
    for (int k = 0; k < K; k += 4) {
        float4 a[4];
#pragma unroll
        for (int i = 0; i < 4; ++i) a[i] = *(const float4*)&As[ty * 4 + i][k];
        float4 w[4];
#pragma unroll
        for (int kk = 0; kk < 4; ++kk) w[kk] = *(const float4*)&Ws[k + kk][tx * 4];
#pragma unroll
        for (int i = 0; i < 4; ++i) {
            float av[4] = {a[i].x, a[i].y, a[i].z, a[i].w};
#pragma unroll
            for (int kk = 0; kk < 4; ++kk) {
                acc[i][0] += av[kk] * w[kk].x;
                acc[i][1] += av[kk] * w[kk].y;
                acc[i][2] += av[kk] * w[kk].z;
                acc[i][3] += av[kk] * w[kk].w;
            }
        }
    }

#pragma unroll
    for (int i = 0; i < 4; ++i) {
        int r = ty * 4 + i;
        if (r < rows) {
            float s = sdinv[r];
            ushort4 v;
            v.x = f2bf(acc[i][0] * s);
            v.y = f2bf(acc[i][1] * s);
            v.z = f2bf(acc[i][2] * s);
            v.w = f2bf(acc[i][3] * s);
            *(ushort4*)&C[(size_t)(block0 + r) * 64 + tx * 4] = v;
        }
    }
}

// ---------------- layers-2/3 linear: bf16 A (K=64) -> bf16 hs (+ dinv pre-scale) --------------
__global__ __launch_bounds__(256) void linear_bf_kernel(
    const unsigned short* __restrict__ A, const float* __restrict__ W,
    const float* __restrict__ dinv, unsigned short* __restrict__ C, int n) {
    const int K = HID;
    __shared__ float As[64][K + 4];
    __shared__ float Ws[K][64];
    int tid = threadIdx.x;
    int tx = tid & 15;
    int ty = tid >> 4;
    int block0 = blockIdx.x * 64;
    int rows = n - block0;
    if (rows > 64) rows = 64;

    const unsigned short* Abase = A + (size_t)block0 * K;
    int total8 = rows * 8;  // 16B (8 bf16) units
    for (int u = tid; u < total8; u += 256) {
        int r = u >> 3;
        int c8 = (u & 7) << 3;
        uint4 raw = *(const uint4*)(Abase + (size_t)r * K + c8);
        float4 a0, a1;
        a0.x = __uint_as_float(raw.x << 16);
        a0.y = __uint_as_float(raw.x & 0xffff0000u);
        a0.z = __uint_as_float(raw.y << 16);
        a0.w = __uint_as_float(raw.y & 0xffff0000u);
        a1.x = __uint_as_float(raw.z << 16);
        a1.y = __uint_as_float(raw.z & 0xffff0000u);
        a1.z = __uint_as_float(raw.w << 16);
        a1.w = __uint_as_float(raw.w & 0xffff0000u);
        *(float4*)&As[r][c8] = a0;
        *(float4*)&As[r][c8 + 4] = a1;
    }
    {
        const float4* Wv = (const float4*)W;
        float4* Wsv = (float4*)&Ws[0][0];
        for (int i = tid; i < K * 16; i += 256) Wsv[i] = Wv[i];
    }
    __syncthreads();

    float acc[4][4] = {};
#pragma unroll 2
    for (int k = 0; k < K; k += 4) {
        float4 a[4];
#pragma unroll
        for (int i = 0; i < 4; ++i) a[i] = *(const float4*)&As[ty * 4 + i][k];
        float4 w[4];
#pragma unroll
        for (int kk = 0; kk < 4; ++kk) w[kk] = *(const float4*)&Ws[k + kk][tx * 4];
#pragma unroll
        for (int i = 0; i < 4; ++i) {
            float av[4] = {a[i].x, a[i].y, a[i].z, a[i].w};
#pragma unroll
            for (int kk = 0; kk < 4; ++kk) {
                acc[i][0] += av[kk] * w[kk].x;
                acc[i][1] += av[kk] * w[kk].y;
                acc[i][2] += av[kk] * w[kk].z;
                acc[i][3] += av[kk] * w[kk].w;
            }
        }
    }

#pragma unroll
    for (int i = 0; i < 4; ++i) {
        int r = ty * 4 + i;
        if (r < rows) {
            float s = dinv[block0 + r];
            ushort4 v;
            v.x = f2bf(acc[i][0] * s);
            v.y = f2bf(acc[i][1] * s);
            v.z = f2bf(acc[i][2] * s);
            v.w = f2bf(acc[i][3] * s);
            *(ushort4*)&C[(size_t)(block0 + r) * 64 + tx * 4] = v;
        }
    }
}

// ------- per-node bf16 gather: 16B/lane loads, 8 lanes/row, 8 edge groups -------------
__global__ __launch_bounds__(256) void gather_kernel(
    const unsigned short* __restrict__ hs, const int* __restrict__ rs,
    const int* __restrict__ csr_src, const float* __restrict__ dinv,
    const float* __restrict__ bias, unsigned short* __restrict__ outp, int n) {
    int wave = threadIdx.x >> 6;
    int node = blockIdx.x * 4 + wave;
    if (node >= n) return;
    int lane = threadIdx.x & 63;
    int eg = lane >> 3;        // edge group 0..7
    int f8 = (lane & 7) << 3;  // feature octet base
    int beg = rs[node], end = rs[node + 1];
    int len = end - beg;
    int q = (len + 7) >> 3;    // per-group quota (contiguous eighth)
    int mb = beg + eg * q;
    int me = mb + q;
    if (me > end) me = end;
    float a[8] = {0.f, 0.f, 0.f, 0.f, 0.f, 0.f, 0.f, 0.f};
    if (eg == 0) {  // self-loop (pre-scaled)
        uint4 r = *(const uint4*)&hs[(size_t)node * 64 + f8];
        acc8(a, r);
    }
    int j = mb;
    for (; j + 3 < me; j += 4) {  // 4 rows in flight
        int s0 = csr_src[j];
        int s1 = csr_src[j + 1];
        int s2 = csr_src[j + 2];
        int s3 = csr_src[j + 3];
        uint4 r0 = *(const uint4*)&hs[(size_t)s0 * 64 + f8];
        uint4 r1 = *(const uint4*)&hs[(size_t)s1 * 64 + f8];
        uint4 r2 = *(const uint4*)&hs[(size_t)s2 * 64 + f8];
        uint4 r3 = *(const uint4*)&hs[(size_t)s3 * 64 + f8];
        acc8(a, r0);
        acc8(a, r1);
        acc8(a, r2);
        acc8(a, r3);
    }
    if (j + 1 < me) {  // 2 rows in flight
        int s0 = csr_src[j];
        int s1 = csr_src[j + 1];
        uint4 r0 = *(const uint4*)&hs[(size_t)s0 * 64 + f8];
        uint4 r1 = *(const uint4*)&hs[(size_t)s1 * 64 + f8];
        acc8(a, r0);
        acc8(a, r1);
        j += 2;
    }
    if (j < me) {
        int s0 = csr_src[j];
        uint4 r0 = *(const uint4*)&hs[(size_t)s0 * 64 + f8];
        acc8(a, r0);
    }
    // merge the 8 edge groups: butterfly over lane bits 3,4,5
#pragma unroll
    for (int k = 0; k < 8; ++k) a[k] += __shfl_xor(a[k], 8);
#pragma unroll
    for (int k = 0; k < 8; ++k) a[k] += __shfl_xor(a[k], 16);
#pragma unroll
    for (int k = 0; k < 8; ++k) a[k] += __shfl_xor(a[k], 32);
    if (eg == 0) {
        float s = dinv[node];
        float4 b0 = *(const float4*)&bias[f8];
        float4 b1 = *(const float4*)&bias[f8 + 4];
        float v0 = fmaxf(a[0] * s + b0.x, 0.f);
        float v1 = fmaxf(a[1] * s + b0.y, 0.f);
        float v2 = fmaxf(a[2] * s + b0.z, 0.f);
        float v3 = fmaxf(a[3] * s + b0.w, 0.f);
        float v4 = fmaxf(a[4] * s + b1.x, 0.f);
        float v5 = fmaxf(a[5] * s + b1.y, 0.f);
        float v6 = fmaxf(a[6] * s + b1.z, 0.f);
        float v7 = fmaxf(a[7] * s + b1.w, 0.f);
        uint4 o;
        o.x = (unsigned)f2bf(v0) | ((unsigned)f2bf(v1) << 16);
        o.y = (unsigned)f2bf(v2) | ((unsigned)f2bf(v3) << 16);
        o.z = (unsigned)f2bf(v4) | ((unsigned)f2bf(v5) << 16);
        o.w = (unsigned)f2bf(v6) | ((unsigned)f2bf(v7) << 16);
        *(uint4*)&outp[(size_t)node * 64 + f8] = o;
    }
}

// ---------------- fused segmented mean-pool + MLP head (16-wave row-sum, bf16 in) ------------
__device__ __forceinline__ int lower_bound_dev(const int* __restrict__ a, int n, int v) {
    int lo = 0, hi = n;
    while (lo < hi) {
        int m = (lo + hi) >> 1;
        if (a[m] < v) lo = m + 1; else hi = m;
    }
    return lo;
}

__global__ __launch_bounds__(1024) void pool_head_kernel(
    const unsigned short* __restrict__ h, const int* __restrict__ batch,
    const float* __restrict__ W1, const float* __restrict__ b1,
    const float* __restrict__ W2, const float* __restrict__ b2,
    float* __restrict__ out, int nNodes, int nGraphs) {
    __shared__ float psum[16][64];
    __shared__ float p[64];
    __shared__ float t64[64];
    int g = blockIdx.x;
    int tid = threadIdx.x;
    int f = tid & 63;
    int q = tid >> 6;  // wave id 0..15
    int lo = lower_bound_dev(batch, nNodes, g);
    int hi = lower_bound_dev(batch, nNodes, g + 1);
    float sum = 0.0f;
    for (int i = lo + q; i < hi; i += 16) sum += bf2f(h[(size_t)i * 64 + f]);
    psum[q][f] = sum;
    __syncthreads();
    if (tid < 64) {  // wave 0 only; intra-wave lockstep below
        float s = 0.0f;
#pragma unroll
        for (int w = 0; w < 16; ++w) s += psum[w][f];
        float inv = 1.0f / fmaxf((float)(hi - lo), 1.0f);
        p[f] = s * inv;
        float acc = b1[f];
#pragma unroll
        for (int k = 0; k < 64; ++k) acc += p[k] * W1[k * 64 + f];
        t64[f] = fmaxf(acc, 0.0f);
        if (f < OUT_DIM) {
            float acc2 = b2[f];
#pragma unroll
            for (int k = 0; k < 64; ++k) acc2 += t64[k] * W2[k * OUT_DIM + f];
            out[g * OUT_DIM + f] = acc2;
        }
        if (g == 0 && f == 0) out[nGraphs * OUT_DIM] = 0.0f;  // trailing scalar output
    }
}

extern "C" void kernel_launch(void* const* d_in, const int* in_sizes, int n_in,
                              void* d_out, int out_size, void* d_ws, size_t ws_size,
                              hipStream_t stream) {
    const float* x      = (const float*)d_in[0];
    const int*   eidx   = (const int*)d_in[1];
    const int*   batch  = (const int*)d_in[2];
    const float* W1     = (const float*)d_in[3];
    const float* b1     = (const float*)d_in[4];
    const float* W2     = (const float*)d_in[5];
    const float* b2     = (const float*)d_in[6];
    const float* W3     = (const float*)d_in[7];
    const float* b3     = (const float*)d_in[8];
    const float* lin_W1 = (const float*)d_in[9];
    const float* lin_b1 = (const float*)d_in[10];
    const float* lin_W2 = (const float*)d_in[11];
    const float* lin_b2 = (const float*)d_in[12];
    float* out = (float*)d_out;

    const int E = in_sizes[1] / 2;
    const int N = N_NODES;
    const int NF = N * HID;
    int epb = (E + NBLK - 1) / NBLK;
    epb = (epb + 7) & ~7;  // multiple of 8 -> chunk bases stay 16B-aligned for int4 reads

    const int* src = eidx;
    const int* dst = eidx + E;

    // workspace layout
    unsigned short* buf1 = (unsigned short*)d_ws;  // hs bf16 [N,64]
    unsigned short* buf2 = buf1 + NF;              // h  bf16 [N,64]
    float* dinv = (float*)(buf2 + NF);             // [N]
    int* bhist  = (int*)(dinv + N);                // [NBLK * NB_BUCK] (in-place counts->bases)
    int* bsum   = bhist + NBLK * NB_BUCK;          // [NB_BUCK]
    int* bstart = bsum + NB_BUCK;                  // [NB_BUCK+1]
    int* rs     = bstart + NB_BUCK + 1;            // [N+1]
    int* csr_src = rs + N + 1;                     // [E]
    unsigned* pairs = (unsigned*)(csr_src + E);    // [E]

    const int TILES = (N + 63) / 64;  // 782 (== NB_BUCK)
    const int GBLK = (N + 3) / 4;     // 12500

    // ---- atomic-free edge build (bscan folded into p2; csr build fused with linear1) ----
    p1_hist_kernel<<<NBLK, BLDT, 0, stream>>>(dst, bhist, E, epb);
    scanA_kernel<<<NB_BUCK, NBLK, 0, stream>>>(bhist, bsum);
    p2_place_kernel<<<NBLK, BLDT, 0, stream>>>(src, dst, bsum, bhist, pairs, bstart, E, epb);

    // ---- layer 1 (fused csr_scatter + linear) ----
    csr_lin1_kernel<<<TILES, 256, 0, stream>>>(pairs, bstart, rs, dinv, csr_src,
                                               x, W1, buf1, N);
    gather_kernel<<<GBLK, 256, 0, stream>>>(buf1, rs, csr_src, dinv, b1, buf2, N);

    // ---- layer 2 ----
    linear_bf_kernel<<<TILES, 256, 0, stream>>>(buf2, W2, dinv, buf1, N);
    gather_kernel<<<GBLK, 256, 0, stream>>>(buf1, rs, csr_src, dinv, b2, buf2, N);

    // ---- layer 3 ----
    linear_bf_kernel<<<TILES, 256, 0, stream>>>(buf2, W3, dinv, buf1, N);
    gather_kernel<<<GBLK, 256, 0, stream>>>(buf1, rs, csr_src, dinv, b3, buf2, N);

    // ---- fused pool + head ----
    pool_head_kernel<<<N_GRAPHS, 1024, 0, stream>>>(buf2, batch, lin_W1, lin_b1, lin_W2, lin_b2,
                                                    out, N, N_GRAPHS);
}

// Round 3
// 219.213 us; speedup vs baseline: 1.1629x; 1.1167x over previous
//
#include <hip/hip_runtime.h>
#include <hip/hip_bf16.h>

#define N_NODES 50000
#define N_EDGES 800000
#define N_GRAPHS 500
#define IN_DIM 128
#define HID 64
#define OUT_DIM 10
#define NB_BUCK ((N_NODES + 63) >> 6)  // 782 buckets of 64 nodes
#define NBLK 256                       // edge chunks (~3128 edges each) -> 1 block/CU
#define BLDT 1024                      // build-kernel block size: 16 waves/CU for latency hiding

// ---- bf16 helpers: exact expand on load, RNE on store ----
__device__ __forceinline__ float bf2f(unsigned short u) {
    return __uint_as_float(((unsigned)u) << 16);
}
__device__ __forceinline__ unsigned short f2bf(float f) {
    unsigned x = __float_as_uint(f);
    x += 0x7fffu + ((x >> 16) & 1u);  // round-to-nearest-even
    return (unsigned short)(x >> 16);
}
// expand 8 bf16 (uint4) and accumulate into 8 floats
__device__ __forceinline__ void acc8(float a[8], uint4 r) {
    a[0] += __uint_as_float(r.x << 16);
    a[1] += __uint_as_float(r.x & 0xffff0000u);
    a[2] += __uint_as_float(r.y << 16);
    a[3] += __uint_as_float(r.y & 0xffff0000u);
    a[4] += __uint_as_float(r.z << 16);
    a[5] += __uint_as_float(r.z & 0xffff0000u);
    a[6] += __uint_as_float(r.w << 16);
    a[7] += __uint_as_float(r.w & 0xffff0000u);
}

// ---------------- P1: per-chunk bucket histogram (LDS, int4 edge reads) ----------------
__global__ __launch_bounds__(BLDT) void p1_hist_kernel(const int* __restrict__ dst,
                                                       int* __restrict__ bhist, int e, int epb) {
    __shared__ int h[NB_BUCK];
    int tid = threadIdx.x;
    int blk = blockIdx.x;
    for (int i = tid; i < NB_BUCK; i += BLDT) h[i] = 0;
    __syncthreads();
    int e0 = blk * epb;
    int e1 = e0 + epb;
    if (e1 > e) e1 = e;
    int i = e0 + tid * 4;
    for (; i + 3 < e1; i += BLDT * 4) {
        int4 d4 = *(const int4*)&dst[i];
        atomicAdd(&h[d4.x >> 6], 1);
        atomicAdd(&h[d4.y >> 6], 1);
        atomicAdd(&h[d4.z >> 6], 1);
        atomicAdd(&h[d4.w >> 6], 1);
    }
    for (int k = i; k < e1 && k < i + 4; ++k) atomicAdd(&h[dst[k] >> 6], 1);
    __syncthreads();
    for (int j = tid; j < NB_BUCK; j += BLDT) bhist[blk * NB_BUCK + j] = h[j];
}

// ---- scanA: per bucket, scan NBLK chunk counts IN PLACE (bhist -> exclusive bases) + total ----
__global__ __launch_bounds__(NBLK) void scanA_kernel(int* __restrict__ bhist,
                                                     int* __restrict__ bsum) {
    __shared__ int s[NBLK];
    int b = blockIdx.x;
    int t = threadIdx.x;  // NBLK threads
    int c = bhist[t * NB_BUCK + b];
    s[t] = c;
    __syncthreads();
    for (int off = 1; off < NBLK; off <<= 1) {
        int x = (t >= off) ? s[t - off] : 0;
        __syncthreads();
        s[t] += x;
        __syncthreads();
    }
    bhist[t * NB_BUCK + b] = s[t] - c;  // in-place: exclusive prefix for chunk t
    if (t == NBLK - 1) bsum[b] = s[t];
}

// ---------------- P2: place edges into bucket-grouped pairs (int4 edge reads) ------
// Each block recomputes the bucket-total exclusive scan in LDS; block 0 publishes bstart.
__global__ __launch_bounds__(BLDT) void p2_place_kernel(
    const int* __restrict__ src, const int* __restrict__ dst,
    const int* __restrict__ bsum, const int* __restrict__ base,
    unsigned* __restrict__ pairs, int* __restrict__ bstart, int e, int epb) {
    __shared__ int h[NB_BUCK];   // local rank counters
    __shared__ int sb[NB_BUCK];  // global segment base for this chunk
    __shared__ int ts[BLDT];     // per-thread totals for the scan
    int tid = threadIdx.x;
    int blk = blockIdx.x;
    int i0 = tid << 2;
    int v0 = 0, v1 = 0, v2 = 0, v3 = 0;
    if (i0 < NB_BUCK) v0 = bsum[i0];
    if (i0 + 1 < NB_BUCK) v1 = bsum[i0 + 1];
    if (i0 + 2 < NB_BUCK) v2 = bsum[i0 + 2];
    if (i0 + 3 < NB_BUCK) v3 = bsum[i0 + 3];
    int tsum = v0 + v1 + v2 + v3;
    ts[tid] = tsum;
    for (int i = tid; i < NB_BUCK; i += BLDT) h[i] = 0;
    __syncthreads();
    for (int off = 1; off < BLDT; off <<= 1) {
        int x = (tid >= off) ? ts[tid - off] : 0;
        __syncthreads();
        ts[tid] += x;
        __syncthreads();
    }
    int excl = ts[tid] - tsum;  // exclusive over threads
    int s0 = excl;
    int s1 = s0 + v0;
    int s2 = s1 + v1;
    int s3 = s2 + v2;
    const int* bb = base + blk * NB_BUCK;
    if (i0 < NB_BUCK) sb[i0] = s0 + bb[i0];
    if (i0 + 1 < NB_BUCK) sb[i0 + 1] = s1 + bb[i0 + 1];
    if (i0 + 2 < NB_BUCK) sb[i0 + 2] = s2 + bb[i0 + 2];
    if (i0 + 3 < NB_BUCK) sb[i0 + 3] = s3 + bb[i0 + 3];
    if (blk == 0) {
        if (i0 < NB_BUCK) bstart[i0] = s0;
        if (i0 + 1 < NB_BUCK) bstart[i0 + 1] = s1;
        if (i0 + 2 < NB_BUCK) bstart[i0 + 2] = s2;
        if (i0 + 3 < NB_BUCK) bstart[i0 + 3] = s3;
        if (tid == 0) bstart[NB_BUCK] = e;
    }
    __syncthreads();
    int e0 = blk * epb;
    int e1 = e0 + epb;
    if (e1 > e) e1 = e;
    int i = e0 + tid * 4;
    for (; i + 3 < e1; i += BLDT * 4) {
        int4 d4 = *(const int4*)&dst[i];
        int4 s4 = *(const int4*)&src[i];
        int b0 = d4.x >> 6, b1 = d4.y >> 6, b2 = d4.z >> 6, b3 = d4.w >> 6;
        int r0 = atomicAdd(&h[b0], 1);
        int r1 = atomicAdd(&h[b1], 1);
        int r2 = atomicAdd(&h[b2], 1);
        int r3 = atomicAdd(&h[b3], 1);
        pairs[sb[b0] + r0] = ((unsigned)(d4.x & 63) << 16) | (unsigned)s4.x;
        pairs[sb[b1] + r1] = ((unsigned)(d4.y & 63) << 16) | (unsigned)s4.y;
        pairs[sb[b2] + r2] = ((unsigned)(d4.z & 63) << 16) | (unsigned)s4.z;
        pairs[sb[b3] + r3] = ((unsigned)(d4.w & 63) << 16) | (unsigned)s4.w;
    }
    for (int k = i; k < e1 && k < i + 4; ++k) {
        int d = dst[k];
        int b = d >> 6;
        int r = atomicAdd(&h[b], 1);
        pairs[sb[b] + r] = ((unsigned)(d & 63) << 16) | (unsigned)src[k];
    }
}

// ------- fused: per-bucket CSR build (rs, dinv, csr_src) + layer-1 linear -----------
__global__ __launch_bounds__(256) void csr_lin1_kernel(
    const unsigned* __restrict__ pairs, const int* __restrict__ bstart,
    int* __restrict__ rs, float* __restrict__ dinv, int* __restrict__ csr_src,
    const float* __restrict__ A, const float* __restrict__ W,
    unsigned short* __restrict__ C, int n) {
    const int K = IN_DIM;
    __shared__ float As[64][K + 4];
    __shared__ float Ws[K][64];
    __shared__ int lcnt[64];
    __shared__ int lcur[64];
    __shared__ float sdinv[64];
    int b = blockIdx.x;
    int tid = threadIdx.x;
    int beg = bstart[b], end = bstart[b + 1];
    if (tid < 64) lcnt[tid] = 0;
    __syncthreads();
    for (int i = beg + tid; i < end; i += 256) atomicAdd(&lcnt[pairs[i] >> 16], 1);
    __syncthreads();
    if (tid < 64) {  // wave 0: scan the 64 node counts
        int c = lcnt[tid];
        int v = c;
#pragma unroll
        for (int off = 1; off < 64; off <<= 1) {
            int t = __shfl_up(v, off);
            if (tid >= off) v += t;
        }
        int excl = v - c;
        int node = b * 64 + tid;
        float dv = rsqrtf((float)(c + 1));
        if (node <= n) {
            rs[node] = beg + excl;  // node==n lands on rs[N]=E (last bucket's tail)
            if (node < n) dinv[node] = dv;
        }
        sdinv[tid] = dv;
        lcur[tid] = beg + excl;
    }
    __syncthreads();
    for (int i = beg + tid; i < end; i += 256) {
        unsigned p = pairs[i];
        int slot = atomicAdd(&lcur[p >> 16], 1);
        csr_src[slot] = (int)(p & 0xffffu);
    }

    // ---- layer-1 linear for nodes [b*64, b*64+64) ----
    int block0 = b * 64;
    int rows = n - block0;
    if (rows > 64) rows = 64;

    const float* Abase = A + (size_t)block0 * K;
    int totalA4 = (rows * K) >> 2;
    for (int i4 = tid; i4 < totalA4; i4 += 256) {
        int i = i4 << 2;
        float4 v = *(const float4*)(Abase + i);
        *(float4*)&As[i / K][i % K] = v;
    }
    {
        const float4* Wv = (const float4*)W;
        float4* Wsv = (float4*)&Ws[0][0];
        for (int i = tid; i < K * 16; i += 256) Wsv[i] = Wv[i];
    }
    __syncthreads();

    int tx = tid & 15;
    int ty = tid >> 4;
    float acc[4][4] = {};
#pragma unroll 2
    for (int k = 0; k < K; k += 4) {
        float4 a[4];
#pragma unroll
        for (int i = 0; i < 4; ++i) a[i] = *(const float4*)&As[ty * 4 + i][k];
        float4 w[4];
#pragma unroll
        for (int kk = 0; kk < 4; ++kk) w[kk] = *(const float4*)&Ws[k + kk][tx * 4];
#pragma unroll
        for (int i = 0; i < 4; ++i) {
            float av[4] = {a[i].x, a[i].y, a[i].z, a[i].w};
#pragma unroll
            for (int kk = 0; kk < 4; ++kk) {
                acc[i][0] += av[kk] * w[kk].x;
                acc[i][1] += av[kk] * w[kk].y;
                acc[i][2] += av[kk] * w[kk].z;
                acc[i][3] += av[kk] * w[kk].w;
            }
        }
    }

#pragma unroll
    for (int i = 0; i < 4; ++i) {
        int r = ty * 4 + i;
        if (r < rows) {
            float s = sdinv[r];
            ushort4 v;
            v.x = f2bf(acc[i][0] * s);
            v.y = f2bf(acc[i][1] * s);
            v.z = f2bf(acc[i][2] * s);
            v.w = f2bf(acc[i][3] * s);
            *(ushort4*)&C[(size_t)(block0 + r) * 64 + tx * 4] = v;
        }
    }
}

// ------- fused: gather(layer i) -> LDS fp32 -> linear(layer i+1) -> bf16 hs_next -------
// One 8-lane group per node (full 64-feature row = 8 lanes x 8 feats); aggregated row
// gets dinv*agg + bias, ReLU, stays fp32 in LDS, feeds the 64x64 GEMM directly.
__global__ __launch_bounds__(256) void gather_lin_kernel(
    const unsigned short* __restrict__ hs, const int* __restrict__ rs,
    const int* __restrict__ csr_src, const float* __restrict__ dinv,
    const float* __restrict__ bias, const float* __restrict__ W,
    unsigned short* __restrict__ C, int n) {
    const int K = HID;
    __shared__ float As[64][K + 4];
    __shared__ float Ws[K][64];
    int tid = threadIdx.x;
    int b = blockIdx.x;
    int block0 = b * 64;
    int rows = n - block0;
    if (rows > 64) rows = 64;

    // stage W (16 KB) — loads overlap the gather phase below
    {
        const float4* Wv = (const float4*)W;
        float4* Wsv = (float4*)&Ws[0][0];
        for (int i = tid; i < K * 16; i += 256) Wsv[i] = Wv[i];
    }

    int grp = tid >> 3;      // 0..31: node group
    int lg = tid & 7;        // lane in group
    int f8 = lg << 3;        // feature octet base
    float4 bb0 = *(const float4*)&bias[f8];
    float4 bb1 = *(const float4*)&bias[f8 + 4];

    for (int r = grp; r < 64; r += 32) {  // 2 rounds of 32 nodes
        int node = block0 + r;
        float a[8] = {0.f, 0.f, 0.f, 0.f, 0.f, 0.f, 0.f, 0.f};
        if (node < n) {
            int beg = rs[node], end = rs[node + 1];
            {   // self row (pre-scaled by dinv at store time)
                uint4 u = *(const uint4*)&hs[(size_t)node * 64 + f8];
                acc8(a, u);
            }
            int j = beg;
            for (; j + 3 < end; j += 4) {  // 4 rows in flight
                int s0 = csr_src[j];
                int s1 = csr_src[j + 1];
                int s2 = csr_src[j + 2];
                int s3 = csr_src[j + 3];
                uint4 r0 = *(const uint4*)&hs[(size_t)s0 * 64 + f8];
                uint4 r1 = *(const uint4*)&hs[(size_t)s1 * 64 + f8];
                uint4 r2 = *(const uint4*)&hs[(size_t)s2 * 64 + f8];
                uint4 r3 = *(const uint4*)&hs[(size_t)s3 * 64 + f8];
                acc8(a, r0);
                acc8(a, r1);
                acc8(a, r2);
                acc8(a, r3);
            }
            if (j + 1 < end) {
                int s0 = csr_src[j];
                int s1 = csr_src[j + 1];
                uint4 r0 = *(const uint4*)&hs[(size_t)s0 * 64 + f8];
                uint4 r1 = *(const uint4*)&hs[(size_t)s1 * 64 + f8];
                acc8(a, r0);
                acc8(a, r1);
                j += 2;
            }
            if (j < end) {
                int s0 = csr_src[j];
                uint4 r0 = *(const uint4*)&hs[(size_t)s0 * 64 + f8];
                acc8(a, r0);
            }
            float sc = dinv[node];
            a[0] = fmaxf(a[0] * sc + bb0.x, 0.f);
            a[1] = fmaxf(a[1] * sc + bb0.y, 0.f);
            a[2] = fmaxf(a[2] * sc + bb0.z, 0.f);
            a[3] = fmaxf(a[3] * sc + bb0.w, 0.f);
            a[4] = fmaxf(a[4] * sc + bb1.x, 0.f);
            a[5] = fmaxf(a[5] * sc + bb1.y, 0.f);
            a[6] = fmaxf(a[6] * sc + bb1.z, 0.f);
            a[7] = fmaxf(a[7] * sc + bb1.w, 0.f);
        }
        float4 w0 = {a[0], a[1], a[2], a[3]};
        float4 w1 = {a[4], a[5], a[6], a[7]};
        *(float4*)&As[r][f8] = w0;       // r>=rows rows get zeros (safe for GEMM)
        *(float4*)&As[r][f8 + 4] = w1;
    }
    __syncthreads();

    // ---- linear: hs_next = (h @ W) * dinv, bf16 out ----
    int tx = tid & 15;
    int ty = tid >> 4;
    float acc[4][4] = {};
#pragma unroll 2
    for (int k = 0; k < K; k += 4) {
        float4 a[4];
#pragma unroll
        for (int i = 0; i < 4; ++i) a[i] = *(const float4*)&As[ty * 4 + i][k];
        float4 w[4];
#pragma unroll
        for (int kk = 0; kk < 4; ++kk) w[kk] = *(const float4*)&Ws[k + kk][tx * 4];
#pragma unroll
        for (int i = 0; i < 4; ++i) {
            float av[4] = {a[i].x, a[i].y, a[i].z, a[i].w};
#pragma unroll
            for (int kk = 0; kk < 4; ++kk) {
                acc[i][0] += av[kk] * w[kk].x;
                acc[i][1] += av[kk] * w[kk].y;
                acc[i][2] += av[kk] * w[kk].z;
                acc[i][3] += av[kk] * w[kk].w;
            }
        }
    }

#pragma unroll
    for (int i = 0; i < 4; ++i) {
        int r = ty * 4 + i;
        if (r < rows) {
            float s = dinv[block0 + r];
            ushort4 v;
            v.x = f2bf(acc[i][0] * s);
            v.y = f2bf(acc[i][1] * s);
            v.z = f2bf(acc[i][2] * s);
            v.w = f2bf(acc[i][3] * s);
            *(ushort4*)&C[(size_t)(block0 + r) * 64 + tx * 4] = v;
        }
    }
}

// ------- final per-node bf16 gather (layer 3): 16B/lane loads, 8 lanes/row, 8 edge groups ----
__global__ __launch_bounds__(256) void gather_kernel(
    const unsigned short* __restrict__ hs, const int* __restrict__ rs,
    const int* __restrict__ csr_src, const float* __restrict__ dinv,
    const float* __restrict__ bias, unsigned short* __restrict__ outp, int n) {
    int wave = threadIdx.x >> 6;
    int node = blockIdx.x * 4 + wave;
    if (node >= n) return;
    int lane = threadIdx.x & 63;
    int eg = lane >> 3;        // edge group 0..7
    int f8 = (lane & 7) << 3;  // feature octet base
    int beg = rs[node], end = rs[node + 1];
    int len = end - beg;
    int q = (len + 7) >> 3;    // per-group quota (contiguous eighth)
    int mb = beg + eg * q;
    int me = mb + q;
    if (me > end) me = end;
    float a[8] = {0.f, 0.f, 0.f, 0.f, 0.f, 0.f, 0.f, 0.f};
    if (eg == 0) {  // self-loop (pre-scaled)
        uint4 r = *(const uint4*)&hs[(size_t)node * 64 + f8];
        acc8(a, r);
    }
    int j = mb;
    for (; j + 3 < me; j += 4) {  // 4 rows in flight
        int s0 = csr_src[j];
        int s1 = csr_src[j + 1];
        int s2 = csr_src[j + 2];
        int s3 = csr_src[j + 3];
        uint4 r0 = *(const uint4*)&hs[(size_t)s0 * 64 + f8];
        uint4 r1 = *(const uint4*)&hs[(size_t)s1 * 64 + f8];
        uint4 r2 = *(const uint4*)&hs[(size_t)s2 * 64 + f8];
        uint4 r3 = *(const uint4*)&hs[(size_t)s3 * 64 + f8];
        acc8(a, r0);
        acc8(a, r1);
        acc8(a, r2);
        acc8(a, r3);
    }
    if (j + 1 < me) {
        int s0 = csr_src[j];
        int s1 = csr_src[j + 1];
        uint4 r0 = *(const uint4*)&hs[(size_t)s0 * 64 + f8];
        uint4 r1 = *(const uint4*)&hs[(size_t)s1 * 64 + f8];
        acc8(a, r0);
        acc8(a, r1);
        j += 2;
    }
    if (j < me) {
        int s0 = csr_src[j];
        uint4 r0 = *(const uint4*)&hs[(size_t)s0 * 64 + f8];
        acc8(a, r0);
    }
    // merge the 8 edge groups: butterfly over lane bits 3,4,5
#pragma unroll
    for (int k = 0; k < 8; ++k) a[k] += __shfl_xor(a[k], 8);
#pragma unroll
    for (int k = 0; k < 8; ++k) a[k] += __shfl_xor(a[k], 16);
#pragma unroll
    for (int k = 0; k < 8; ++k) a[k] += __shfl_xor(a[k], 32);
    if (eg == 0) {
        float s = dinv[node];
        float4 b0 = *(const float4*)&bias[f8];
        float4 b1 = *(const float4*)&bias[f8 + 4];
        float v0 = fmaxf(a[0] * s + b0.x, 0.f);
        float v1 = fmaxf(a[1] * s + b0.y, 0.f);
        float v2 = fmaxf(a[2] * s + b0.z, 0.f);
        float v3 = fmaxf(a[3] * s + b0.w, 0.f);
        float v4 = fmaxf(a[4] * s + b1.x, 0.f);
        float v5 = fmaxf(a[5] * s + b1.y, 0.f);
        float v6 = fmaxf(a[6] * s + b1.z, 0.f);
        float v7 = fmaxf(a[7] * s + b1.w, 0.f);
        uint4 o;
        o.x = (unsigned)f2bf(v0) | ((unsigned)f2bf(v1) << 16);
        o.y = (unsigned)f2bf(v2) | ((unsigned)f2bf(v3) << 16);
        o.z = (unsigned)f2bf(v4) | ((unsigned)f2bf(v5) << 16);
        o.w = (unsigned)f2bf(v6) | ((unsigned)f2bf(v7) << 16);
        *(uint4*)&outp[(size_t)node * 64 + f8] = o;
    }
}

// ---------------- fused segmented mean-pool + MLP head (16-wave row-sum, bf16 in) ------------
__device__ __forceinline__ int lower_bound_dev(const int* __restrict__ a, int n, int v) {
    int lo = 0, hi = n;
    while (lo < hi) {
        int m = (lo + hi) >> 1;
        if (a[m] < v) lo = m + 1; else hi = m;
    }
    return lo;
}

__global__ __launch_bounds__(1024) void pool_head_kernel(
    const unsigned short* __restrict__ h, const int* __restrict__ batch,
    const float* __restrict__ W1, const float* __restrict__ b1,
    const float* __restrict__ W2, const float* __restrict__ b2,
    float* __restrict__ out, int nNodes, int nGraphs) {
    __shared__ float psum[16][64];
    __shared__ float p[64];
    __shared__ float t64[64];
    int g = blockIdx.x;
    int tid = threadIdx.x;
    int f = tid & 63;
    int q = tid >> 6;  // wave id 0..15
    int lo = lower_bound_dev(batch, nNodes, g);
    int hi = lower_bound_dev(batch, nNodes, g + 1);
    float sum = 0.0f;
    for (int i = lo + q; i < hi; i += 16) sum += bf2f(h[(size_t)i * 64 + f]);
    psum[q][f] = sum;
    __syncthreads();
    if (tid < 64) {  // wave 0 only; intra-wave lockstep below
        float s = 0.0f;
#pragma unroll
        for (int w = 0; w < 16; ++w) s += psum[w][f];
        float inv = 1.0f / fmaxf((float)(hi - lo), 1.0f);
        p[f] = s * inv;
        float acc = b1[f];
#pragma unroll
        for (int k = 0; k < 64; ++k) acc += p[k] * W1[k * 64 + f];
        t64[f] = fmaxf(acc, 0.0f);
        if (f < OUT_DIM) {
            float acc2 = b2[f];
#pragma unroll
            for (int k = 0; k < 64; ++k) acc2 += t64[k] * W2[k * OUT_DIM + f];
            out[g * OUT_DIM + f] = acc2;
        }
        if (g == 0 && f == 0) out[nGraphs * OUT_DIM] = 0.0f;  // trailing scalar output
    }
}

extern "C" void kernel_launch(void* const* d_in, const int* in_sizes, int n_in,
                              void* d_out, int out_size, void* d_ws, size_t ws_size,
                              hipStream_t stream) {
    const float* x      = (const float*)d_in[0];
    const int*   eidx   = (const int*)d_in[1];
    const int*   batch  = (const int*)d_in[2];
    const float* W1     = (const float*)d_in[3];
    const float* b1     = (const float*)d_in[4];
    const float* W2     = (const float*)d_in[5];
    const float* b2     = (const float*)d_in[6];
    const float* W3     = (const float*)d_in[7];
    const float* b3     = (const float*)d_in[8];
    const float* lin_W1 = (const float*)d_in[9];
    const float* lin_b1 = (const float*)d_in[10];
    const float* lin_W2 = (const float*)d_in[11];
    const float* lin_b2 = (const float*)d_in[12];
    float* out = (float*)d_out;

    const int E = in_sizes[1] / 2;
    const int N = N_NODES;
    const int NF = N * HID;
    int epb = (E + NBLK - 1) / NBLK;
    epb = (epb + 7) & ~7;  // multiple of 8 -> chunk bases stay 16B-aligned for int4 reads

    const int* src = eidx;
    const int* dst = eidx + E;

    // workspace layout
    unsigned short* buf1 = (unsigned short*)d_ws;  // hs bf16 [N,64]
    unsigned short* buf2 = buf1 + NF;              // h  bf16 [N,64]
    float* dinv = (float*)(buf2 + NF);             // [N]
    int* bhist  = (int*)(dinv + N);                // [NBLK * NB_BUCK] (in-place counts->bases)
    int* bsum   = bhist + NBLK * NB_BUCK;          // [NB_BUCK]
    int* bstart = bsum + NB_BUCK;                  // [NB_BUCK+1]
    int* rs     = bstart + NB_BUCK + 1;            // [N+1]
    int* csr_src = rs + N + 1;                     // [E]
    unsigned* pairs = (unsigned*)(csr_src + E);    // [E]

    const int TILES = (N + 63) / 64;  // 782 (== NB_BUCK)
    const int GBLK = (N + 3) / 4;     // 12500

    // ---- atomic-free edge build ----
    p1_hist_kernel<<<NBLK, BLDT, 0, stream>>>(dst, bhist, E, epb);
    scanA_kernel<<<NB_BUCK, NBLK, 0, stream>>>(bhist, bsum);
    p2_place_kernel<<<NBLK, BLDT, 0, stream>>>(src, dst, bsum, bhist, pairs, bstart, E, epb);

    // ---- layer 1 (fused csr_scatter + linear1) -> hs1 ----
    csr_lin1_kernel<<<TILES, 256, 0, stream>>>(pairs, bstart, rs, dinv, csr_src,
                                               x, W1, buf1, N);

    // ---- gather1 + linear2 fused -> hs2 ----
    gather_lin_kernel<<<TILES, 256, 0, stream>>>(buf1, rs, csr_src, dinv, b1, W2, buf2, N);

    // ---- gather2 + linear3 fused -> hs3 ----
    gather_lin_kernel<<<TILES, 256, 0, stream>>>(buf2, rs, csr_src, dinv, b2, W3, buf1, N);

    // ---- gather3 -> h3 (bf16 for pool) ----
    gather_kernel<<<GBLK, 256, 0, stream>>>(buf1, rs, csr_src, dinv, b3, buf2, N);

    // ---- fused pool + head ----
    pool_head_kernel<<<N_GRAPHS, 1024, 0, stream>>>(buf2, batch, lin_W1, lin_b1, lin_W2, lin_b2,
                                                    out, N, N_GRAPHS);
}

// Round 4
// 205.460 us; speedup vs baseline: 1.2408x; 1.0669x over previous
//
#include <hip/hip_runtime.h>
#include <hip/hip_bf16.h>

#define N_NODES 50000
#define N_EDGES 800000
#define N_GRAPHS 500
#define IN_DIM 128
#define HID 64
#define OUT_DIM 10
#define NB_BUCK ((N_NODES + 63) >> 6)  // 782 buckets of 64 nodes
#define NBLK 256                       // edge chunks (~3128 edges each) -> 1 block/CU
#define BLDT 1024                      // build-kernel block size: 16 waves/CU for latency hiding

// ---- bf16 helpers: exact expand on load, RNE on store ----
__device__ __forceinline__ float bf2f(unsigned short u) {
    return __uint_as_float(((unsigned)u) << 16);
}
__device__ __forceinline__ unsigned short f2bf(float f) {
    unsigned x = __float_as_uint(f);
    x += 0x7fffu + ((x >> 16) & 1u);  // round-to-nearest-even
    return (unsigned short)(x >> 16);
}
// expand 8 bf16 (uint4) and accumulate into 8 floats
__device__ __forceinline__ void acc8(float a[8], uint4 r) {
    a[0] += __uint_as_float(r.x << 16);
    a[1] += __uint_as_float(r.x & 0xffff0000u);
    a[2] += __uint_as_float(r.y << 16);
    a[3] += __uint_as_float(r.y & 0xffff0000u);
    a[4] += __uint_as_float(r.z << 16);
    a[5] += __uint_as_float(r.z & 0xffff0000u);
    a[6] += __uint_as_float(r.w << 16);
    a[7] += __uint_as_float(r.w & 0xffff0000u);
}

// gather one node's neighborhood into a[8] (this lane's 8-feature octet), 8 rows in flight
__device__ __forceinline__ void gather_node(const unsigned short* __restrict__ hs,
                                            const int* __restrict__ csr_src,
                                            int node, int beg, int end, int f8, float a[8]) {
    {   // self row (pre-scaled by dinv at store time)
        uint4 u = *(const uint4*)&hs[(size_t)node * 64 + f8];
        acc8(a, u);
    }
    int j = beg;
    for (; j + 7 < end; j += 8) {  // 8 rows in flight
        int s0 = csr_src[j];
        int s1 = csr_src[j + 1];
        int s2 = csr_src[j + 2];
        int s3 = csr_src[j + 3];
        int s4 = csr_src[j + 4];
        int s5 = csr_src[j + 5];
        int s6 = csr_src[j + 6];
        int s7 = csr_src[j + 7];
        uint4 r0 = *(const uint4*)&hs[(size_t)s0 * 64 + f8];
        uint4 r1 = *(const uint4*)&hs[(size_t)s1 * 64 + f8];
        uint4 r2 = *(const uint4*)&hs[(size_t)s2 * 64 + f8];
        uint4 r3 = *(const uint4*)&hs[(size_t)s3 * 64 + f8];
        uint4 r4 = *(const uint4*)&hs[(size_t)s4 * 64 + f8];
        uint4 r5 = *(const uint4*)&hs[(size_t)s5 * 64 + f8];
        uint4 r6 = *(const uint4*)&hs[(size_t)s6 * 64 + f8];
        uint4 r7 = *(const uint4*)&hs[(size_t)s7 * 64 + f8];
        acc8(a, r0); acc8(a, r1); acc8(a, r2); acc8(a, r3);
        acc8(a, r4); acc8(a, r5); acc8(a, r6); acc8(a, r7);
    }
    if (j + 3 < end) {  // 4 rows
        int s0 = csr_src[j];
        int s1 = csr_src[j + 1];
        int s2 = csr_src[j + 2];
        int s3 = csr_src[j + 3];
        uint4 r0 = *(const uint4*)&hs[(size_t)s0 * 64 + f8];
        uint4 r1 = *(const uint4*)&hs[(size_t)s1 * 64 + f8];
        uint4 r2 = *(const uint4*)&hs[(size_t)s2 * 64 + f8];
        uint4 r3 = *(const uint4*)&hs[(size_t)s3 * 64 + f8];
        acc8(a, r0); acc8(a, r1); acc8(a, r2); acc8(a, r3);
        j += 4;
    }
    if (j + 1 < end) {  // 2 rows
        int s0 = csr_src[j];
        int s1 = csr_src[j + 1];
        uint4 r0 = *(const uint4*)&hs[(size_t)s0 * 64 + f8];
        uint4 r1 = *(const uint4*)&hs[(size_t)s1 * 64 + f8];
        acc8(a, r0); acc8(a, r1);
        j += 2;
    }
    if (j < end) {
        int s0 = csr_src[j];
        uint4 r0 = *(const uint4*)&hs[(size_t)s0 * 64 + f8];
        acc8(a, r0);
    }
}

// ---------------- P1: per-chunk bucket histogram (LDS, int4 edge reads) + gsum zero ----------
__global__ __launch_bounds__(BLDT) void p1_hist_kernel(const int* __restrict__ dst,
                                                       int* __restrict__ bhist,
                                                       float* __restrict__ gsum,
                                                       int e, int epb) {
    __shared__ int h[NB_BUCK];
    int tid = threadIdx.x;
    int blk = blockIdx.x;
    {   // zero the pool accumulator (consumed much later by gather_pool)
        int z = blk * BLDT + tid;
        if (z < N_GRAPHS * HID) gsum[z] = 0.0f;
    }
    for (int i = tid; i < NB_BUCK; i += BLDT) h[i] = 0;
    __syncthreads();
    int e0 = blk * epb;
    int e1 = e0 + epb;
    if (e1 > e) e1 = e;
    int i = e0 + tid * 4;
    for (; i + 3 < e1; i += BLDT * 4) {
        int4 d4 = *(const int4*)&dst[i];
        atomicAdd(&h[d4.x >> 6], 1);
        atomicAdd(&h[d4.y >> 6], 1);
        atomicAdd(&h[d4.z >> 6], 1);
        atomicAdd(&h[d4.w >> 6], 1);
    }
    for (int k = i; k < e1 && k < i + 4; ++k) atomicAdd(&h[dst[k] >> 6], 1);
    __syncthreads();
    for (int j = tid; j < NB_BUCK; j += BLDT) bhist[blk * NB_BUCK + j] = h[j];
}

// ---- scanA: per bucket, scan NBLK chunk counts IN PLACE (bhist -> exclusive bases) + total ----
__global__ __launch_bounds__(NBLK) void scanA_kernel(int* __restrict__ bhist,
                                                     int* __restrict__ bsum) {
    __shared__ int s[NBLK];
    int b = blockIdx.x;
    int t = threadIdx.x;  // NBLK threads
    int c = bhist[t * NB_BUCK + b];
    s[t] = c;
    __syncthreads();
    for (int off = 1; off < NBLK; off <<= 1) {
        int x = (t >= off) ? s[t - off] : 0;
        __syncthreads();
        s[t] += x;
        __syncthreads();
    }
    bhist[t * NB_BUCK + b] = s[t] - c;  // in-place: exclusive prefix for chunk t
    if (t == NBLK - 1) bsum[b] = s[t];
}

// ---------------- P2: place edges into bucket-grouped pairs (int4 edge reads) ------
// Each block recomputes the bucket-total exclusive scan in LDS; block 0 publishes bstart.
__global__ __launch_bounds__(BLDT) void p2_place_kernel(
    const int* __restrict__ src, const int* __restrict__ dst,
    const int* __restrict__ bsum, const int* __restrict__ base,
    unsigned* __restrict__ pairs, int* __restrict__ bstart, int e, int epb) {
    __shared__ int h[NB_BUCK];   // local rank counters
    __shared__ int sb[NB_BUCK];  // global segment base for this chunk
    __shared__ int ts[BLDT];     // per-thread totals for the scan
    int tid = threadIdx.x;
    int blk = blockIdx.x;
    int i0 = tid << 2;
    int v0 = 0, v1 = 0, v2 = 0, v3 = 0;
    if (i0 < NB_BUCK) v0 = bsum[i0];
    if (i0 + 1 < NB_BUCK) v1 = bsum[i0 + 1];
    if (i0 + 2 < NB_BUCK) v2 = bsum[i0 + 2];
    if (i0 + 3 < NB_BUCK) v3 = bsum[i0 + 3];
    int tsum = v0 + v1 + v2 + v3;
    ts[tid] = tsum;
    for (int i = tid; i < NB_BUCK; i += BLDT) h[i] = 0;
    __syncthreads();
    for (int off = 1; off < BLDT; off <<= 1) {
        int x = (tid >= off) ? ts[tid - off] : 0;
        __syncthreads();
        ts[tid] += x;
        __syncthreads();
    }
    int excl = ts[tid] - tsum;  // exclusive over threads
    int s0 = excl;
    int s1 = s0 + v0;
    int s2 = s1 + v1;
    int s3 = s2 + v2;
    const int* bb = base + blk * NB_BUCK;
    if (i0 < NB_BUCK) sb[i0] = s0 + bb[i0];
    if (i0 + 1 < NB_BUCK) sb[i0 + 1] = s1 + bb[i0 + 1];
    if (i0 + 2 < NB_BUCK) sb[i0 + 2] = s2 + bb[i0 + 2];
    if (i0 + 3 < NB_BUCK) sb[i0 + 3] = s3 + bb[i0 + 3];
    if (blk == 0) {
        if (i0 < NB_BUCK) bstart[i0] = s0;
        if (i0 + 1 < NB_BUCK) bstart[i0 + 1] = s1;
        if (i0 + 2 < NB_BUCK) bstart[i0 + 2] = s2;
        if (i0 + 3 < NB_BUCK) bstart[i0 + 3] = s3;
        if (tid == 0) bstart[NB_BUCK] = e;
    }
    __syncthreads();
    int e0 = blk * epb;
    int e1 = e0 + epb;
    if (e1 > e) e1 = e;
    int i = e0 + tid * 4;
    for (; i + 3 < e1; i += BLDT * 4) {
        int4 d4 = *(const int4*)&dst[i];
        int4 s4 = *(const int4*)&src[i];
        int b0 = d4.x >> 6, b1 = d4.y >> 6, b2 = d4.z >> 6, b3 = d4.w >> 6;
        int r0 = atomicAdd(&h[b0], 1);
        int r1 = atomicAdd(&h[b1], 1);
        int r2 = atomicAdd(&h[b2], 1);
        int r3 = atomicAdd(&h[b3], 1);
        pairs[sb[b0] + r0] = ((unsigned)(d4.x & 63) << 16) | (unsigned)s4.x;
        pairs[sb[b1] + r1] = ((unsigned)(d4.y & 63) << 16) | (unsigned)s4.y;
        pairs[sb[b2] + r2] = ((unsigned)(d4.z & 63) << 16) | (unsigned)s4.z;
        pairs[sb[b3] + r3] = ((unsigned)(d4.w & 63) << 16) | (unsigned)s4.w;
    }
    for (int k = i; k < e1 && k < i + 4; ++k) {
        int d = dst[k];
        int b = d >> 6;
        int r = atomicAdd(&h[b], 1);
        pairs[sb[b] + r] = ((unsigned)(d & 63) << 16) | (unsigned)src[k];
    }
}

// ------- fused: per-bucket CSR build (rs, dinv, csr_src) + layer-1 linear -----------
__global__ __launch_bounds__(256) void csr_lin1_kernel(
    const unsigned* __restrict__ pairs, const int* __restrict__ bstart,
    int* __restrict__ rs, float* __restrict__ dinv, int* __restrict__ csr_src,
    const float* __restrict__ A, const float* __restrict__ W,
    unsigned short* __restrict__ C, int n) {
    const int K = IN_DIM;
    __shared__ float As[64][K + 4];
    __shared__ float Ws[K][64];
    __shared__ int lcnt[64];
    __shared__ int lcur[64];
    __shared__ float sdinv[64];
    int b = blockIdx.x;
    int tid = threadIdx.x;
    int beg = bstart[b], end = bstart[b + 1];
    if (tid < 64) lcnt[tid] = 0;
    __syncthreads();
    for (int i = beg + tid; i < end; i += 256) atomicAdd(&lcnt[pairs[i] >> 16], 1);
    __syncthreads();
    if (tid < 64) {  // wave 0: scan the 64 node counts
        int c = lcnt[tid];
        int v = c;
#pragma unroll
        for (int off = 1; off < 64; off <<= 1) {
            int t = __shfl_up(v, off);
            if (tid >= off) v += t;
        }
        int excl = v - c;
        int node = b * 64 + tid;
        float dv = rsqrtf((float)(c + 1));
        if (node <= n) {
            rs[node] = beg + excl;  // node==n lands on rs[N]=E (last bucket's tail)
            if (node < n) dinv[node] = dv;
        }
        sdinv[tid] = dv;
        lcur[tid] = beg + excl;
    }
    __syncthreads();
    for (int i = beg + tid; i < end; i += 256) {
        unsigned p = pairs[i];
        int slot = atomicAdd(&lcur[p >> 16], 1);
        csr_src[slot] = (int)(p & 0xffffu);
    }

    // ---- layer-1 linear for nodes [b*64, b*64+64) ----
    int block0 = b * 64;
    int rows = n - block0;
    if (rows > 64) rows = 64;

    const float* Abase = A + (size_t)block0 * K;
    int totalA4 = (rows * K) >> 2;
    for (int i4 = tid; i4 < totalA4; i4 += 256) {
        int i = i4 << 2;
        float4 v = *(const float4*)(Abase + i);
        *(float4*)&As[i / K][i % K] = v;
    }
    {
        const float4* Wv = (const float4*)W;
        float4* Wsv = (float4*)&Ws[0][0];
        for (int i = tid; i < K * 16; i += 256) Wsv[i] = Wv[i];
    }
    __syncthreads();

    int tx = tid & 15;
    int ty = tid >> 4;
    float acc[4][4] = {};
#pragma unroll 2
    for (int k = 0; k < K; k += 4) {
        float4 a[4];
#pragma unroll
        for (int i = 0; i < 4; ++i) a[i] = *(const float4*)&As[ty * 4 + i][k];
        float4 w[4];
#pragma unroll
        for (int kk = 0; kk < 4; ++kk) w[kk] = *(const float4*)&Ws[k + kk][tx * 4];
#pragma unroll
        for (int i = 0; i < 4; ++i) {
            float av[4] = {a[i].x, a[i].y, a[i].z, a[i].w};
#pragma unroll
            for (int kk = 0; kk < 4; ++kk) {
                acc[i][0] += av[kk] * w[kk].x;
                acc[i][1] += av[kk] * w[kk].y;
                acc[i][2] += av[kk] * w[kk].z;
                acc[i][3] += av[kk] * w[kk].w;
            }
        }
    }

#pragma unroll
    for (int i = 0; i < 4; ++i) {
        int r = ty * 4 + i;
        if (r < rows) {
            float s = sdinv[r];
            ushort4 v;
            v.x = f2bf(acc[i][0] * s);
            v.y = f2bf(acc[i][1] * s);
            v.z = f2bf(acc[i][2] * s);
            v.w = f2bf(acc[i][3] * s);
            *(ushort4*)&C[(size_t)(block0 + r) * 64 + tx * 4] = v;
        }
    }
}

// ------- fused: gather(layer i) -> LDS fp32 -> linear(layer i+1) -> bf16 hs_next -------
// 32 nodes/block (1563 blocks -> ~6 blocks/CU = 24 waves/CU), 8 rows in flight per lane.
__global__ __launch_bounds__(256) void gather_lin_kernel(
    const unsigned short* __restrict__ hs, const int* __restrict__ rs,
    const int* __restrict__ csr_src, const float* __restrict__ dinv,
    const float* __restrict__ bias, const float* __restrict__ W,
    unsigned short* __restrict__ C, int n) {
    const int K = HID;
    __shared__ float As[32][K + 4];
    __shared__ float Ws[K][64];
    int tid = threadIdx.x;
    int block0 = blockIdx.x * 32;
    int rows = n - block0;
    if (rows > 32) rows = 32;

    // stage W (16 KB) — loads overlap the gather phase below
    {
        const float4* Wv = (const float4*)W;
        float4* Wsv = (float4*)&Ws[0][0];
        for (int i = tid; i < K * 16; i += 256) Wsv[i] = Wv[i];
    }

    int grp = tid >> 3;      // 0..31: one node per 8-lane group
    int lg = tid & 7;        // lane in group
    int f8 = lg << 3;        // feature octet base
    float4 bb0 = *(const float4*)&bias[f8];
    float4 bb1 = *(const float4*)&bias[f8 + 4];

    int node = block0 + grp;
    float a[8] = {0.f, 0.f, 0.f, 0.f, 0.f, 0.f, 0.f, 0.f};
    if (node < n) {
        int beg = rs[node], end = rs[node + 1];
        gather_node(hs, csr_src, node, beg, end, f8, a);
        float sc = dinv[node];
        a[0] = fmaxf(a[0] * sc + bb0.x, 0.f);
        a[1] = fmaxf(a[1] * sc + bb0.y, 0.f);
        a[2] = fmaxf(a[2] * sc + bb0.z, 0.f);
        a[3] = fmaxf(a[3] * sc + bb0.w, 0.f);
        a[4] = fmaxf(a[4] * sc + bb1.x, 0.f);
        a[5] = fmaxf(a[5] * sc + bb1.y, 0.f);
        a[6] = fmaxf(a[6] * sc + bb1.z, 0.f);
        a[7] = fmaxf(a[7] * sc + bb1.w, 0.f);
    }
    {
        float4 w0 = {a[0], a[1], a[2], a[3]};
        float4 w1 = {a[4], a[5], a[6], a[7]};
        *(float4*)&As[grp][f8] = w0;   // node>=n rows get zeros (safe for GEMM)
        *(float4*)&As[grp][f8 + 4] = w1;
    }
    __syncthreads();

    // ---- linear: hs_next = (h @ W) * dinv, bf16 out; 2 rows per thread ----
    int tx = tid & 15;
    int ty = tid >> 4;
    float acc[2][4] = {};
#pragma unroll 2
    for (int k = 0; k < K; k += 4) {
        float4 aa[2];
#pragma unroll
        for (int i = 0; i < 2; ++i) aa[i] = *(const float4*)&As[ty * 2 + i][k];
        float4 w[4];
#pragma unroll
        for (int kk = 0; kk < 4; ++kk) w[kk] = *(const float4*)&Ws[k + kk][tx * 4];
#pragma unroll
        for (int i = 0; i < 2; ++i) {
            float av[4] = {aa[i].x, aa[i].y, aa[i].z, aa[i].w};
#pragma unroll
            for (int kk = 0; kk < 4; ++kk) {
                acc[i][0] += av[kk] * w[kk].x;
                acc[i][1] += av[kk] * w[kk].y;
                acc[i][2] += av[kk] * w[kk].z;
                acc[i][3] += av[kk] * w[kk].w;
            }
        }
    }

#pragma unroll
    for (int i = 0; i < 2; ++i) {
        int r = ty * 2 + i;
        if (r < rows) {
            float s = dinv[block0 + r];
            ushort4 v;
            v.x = f2bf(acc[i][0] * s);
            v.y = f2bf(acc[i][1] * s);
            v.z = f2bf(acc[i][2] * s);
            v.w = f2bf(acc[i][3] * s);
            *(ushort4*)&C[(size_t)(block0 + r) * 64 + tx * 4] = v;
        }
    }
}

// ------- fused: final gather (layer 3) + segmented per-graph pool partials --------
// 32 nodes/block; aggregated rows stay fp32 in LDS; per-graph run-sums flushed via
// fp32 atomics into gsum[NGRAPHS][64] (zeroed by p1). batch is sorted.
__global__ __launch_bounds__(256) void gather_pool_kernel(
    const unsigned short* __restrict__ hs, const int* __restrict__ rs,
    const int* __restrict__ csr_src, const float* __restrict__ dinv,
    const float* __restrict__ bias, const int* __restrict__ batch,
    float* __restrict__ gsum, int n) {
    __shared__ float As[32][68];
    int tid = threadIdx.x;
    int block0 = blockIdx.x * 32;
    int rows = n - block0;
    if (rows > 32) rows = 32;

    int grp = tid >> 3;
    int lg = tid & 7;
    int f8 = lg << 3;
    float4 bb0 = *(const float4*)&bias[f8];
    float4 bb1 = *(const float4*)&bias[f8 + 4];

    int node = block0 + grp;
    float a[8] = {0.f, 0.f, 0.f, 0.f, 0.f, 0.f, 0.f, 0.f};
    if (node < n) {
        int beg = rs[node], end = rs[node + 1];
        gather_node(hs, csr_src, node, beg, end, f8, a);
        float sc = dinv[node];
        a[0] = fmaxf(a[0] * sc + bb0.x, 0.f);
        a[1] = fmaxf(a[1] * sc + bb0.y, 0.f);
        a[2] = fmaxf(a[2] * sc + bb0.z, 0.f);
        a[3] = fmaxf(a[3] * sc + bb0.w, 0.f);
        a[4] = fmaxf(a[4] * sc + bb1.x, 0.f);
        a[5] = fmaxf(a[5] * sc + bb1.y, 0.f);
        a[6] = fmaxf(a[6] * sc + bb1.z, 0.f);
        a[7] = fmaxf(a[7] * sc + bb1.w, 0.f);
    }
    {
        float4 w0 = {a[0], a[1], a[2], a[3]};
        float4 w1 = {a[4], a[5], a[6], a[7]};
        *(float4*)&As[grp][f8] = w0;
        *(float4*)&As[grp][f8 + 4] = w1;
    }
    __syncthreads();

    // segmented flush: wave q walks rows [q*8, q*8+8), feature f; run-sum per graph
    int q = tid >> 6;   // 0..3
    int f = tid & 63;
    int r0 = q * 8;
    int r1 = r0 + 8;
    if (r1 > rows) r1 = rows;
    if (r0 < rows) {
        int gprev = batch[block0 + r0];
        float run = 0.0f;
        for (int r = r0; r < r1; ++r) {
            int g = batch[block0 + r];
            if (g != gprev) {
                atomicAdd(&gsum[(size_t)gprev * 64 + f], run);
                run = 0.0f;
                gprev = g;
            }
            run += As[r][f];
        }
        atomicAdd(&gsum[(size_t)gprev * 64 + f], run);
    }
}

// ---------------- tiny head: mean + MLP from gsum[G][64] ----------------
__device__ __forceinline__ int lower_bound_dev(const int* __restrict__ a, int n, int v) {
    int lo = 0, hi = n;
    while (lo < hi) {
        int m = (lo + hi) >> 1;
        if (a[m] < v) lo = m + 1; else hi = m;
    }
    return lo;
}

__global__ __launch_bounds__(64) void head_kernel(
    const float* __restrict__ gsum, const int* __restrict__ batch,
    const float* __restrict__ W1, const float* __restrict__ b1,
    const float* __restrict__ W2, const float* __restrict__ b2,
    float* __restrict__ out, int nNodes, int nGraphs) {
    __shared__ float p[64];
    __shared__ float t64[64];
    int g = blockIdx.x;
    int f = threadIdx.x;  // 0..63, one wave
    int lo = lower_bound_dev(batch, nNodes, g);
    int hi = lower_bound_dev(batch, nNodes, g + 1);
    float inv = 1.0f / fmaxf((float)(hi - lo), 1.0f);
    p[f] = gsum[(size_t)g * 64 + f] * inv;
    __syncthreads();
    float acc = b1[f];
#pragma unroll
    for (int k = 0; k < 64; ++k) acc += p[k] * W1[k * 64 + f];
    t64[f] = fmaxf(acc, 0.0f);
    __syncthreads();
    if (f < OUT_DIM) {
        float acc2 = b2[f];
#pragma unroll
        for (int k = 0; k < 64; ++k) acc2 += t64[k] * W2[k * OUT_DIM + f];
        out[g * OUT_DIM + f] = acc2;
    }
    if (g == 0 && f == 0) out[nGraphs * OUT_DIM] = 0.0f;  // trailing scalar output
}

extern "C" void kernel_launch(void* const* d_in, const int* in_sizes, int n_in,
                              void* d_out, int out_size, void* d_ws, size_t ws_size,
                              hipStream_t stream) {
    const float* x      = (const float*)d_in[0];
    const int*   eidx   = (const int*)d_in[1];
    const int*   batch  = (const int*)d_in[2];
    const float* W1     = (const float*)d_in[3];
    const float* b1     = (const float*)d_in[4];
    const float* W2     = (const float*)d_in[5];
    const float* b2     = (const float*)d_in[6];
    const float* W3     = (const float*)d_in[7];
    const float* b3     = (const float*)d_in[8];
    const float* lin_W1 = (const float*)d_in[9];
    const float* lin_b1 = (const float*)d_in[10];
    const float* lin_W2 = (const float*)d_in[11];
    const float* lin_b2 = (const float*)d_in[12];
    float* out = (float*)d_out;

    const int E = in_sizes[1] / 2;
    const int N = N_NODES;
    const int NF = N * HID;
    int epb = (E + NBLK - 1) / NBLK;
    epb = (epb + 7) & ~7;  // multiple of 8 -> chunk bases stay 16B-aligned for int4 reads

    const int* src = eidx;
    const int* dst = eidx + E;

    // workspace layout
    unsigned short* buf1 = (unsigned short*)d_ws;  // hs bf16 [N,64]
    unsigned short* buf2 = buf1 + NF;              // h  bf16 [N,64]
    float* dinv = (float*)(buf2 + NF);             // [N]
    int* bhist  = (int*)(dinv + N);                // [NBLK * NB_BUCK] (in-place counts->bases)
    int* bsum   = bhist + NBLK * NB_BUCK;          // [NB_BUCK]
    int* bstart = bsum + NB_BUCK;                  // [NB_BUCK+1]
    int* rs     = bstart + NB_BUCK + 1;            // [N+1]
    int* csr_src = rs + N + 1;                     // [E]
    unsigned* pairs = (unsigned*)(csr_src + E);    // [E]
    float* gsum = (float*)(pairs + E);             // [N_GRAPHS * HID] pool partials

    const int TILES = (N + 63) / 64;   // 782 (== NB_BUCK)
    const int G32 = (N + 31) / 32;     // 1563 half-bucket blocks

    // ---- atomic-free edge build (+ gsum zero in p1) ----
    p1_hist_kernel<<<NBLK, BLDT, 0, stream>>>(dst, bhist, gsum, E, epb);
    scanA_kernel<<<NB_BUCK, NBLK, 0, stream>>>(bhist, bsum);
    p2_place_kernel<<<NBLK, BLDT, 0, stream>>>(src, dst, bsum, bhist, pairs, bstart, E, epb);

    // ---- layer 1 (fused csr_scatter + linear1) -> hs1 ----
    csr_lin1_kernel<<<TILES, 256, 0, stream>>>(pairs, bstart, rs, dinv, csr_src,
                                               x, W1, buf1, N);

    // ---- gather1 + linear2 fused -> hs2 ----
    gather_lin_kernel<<<G32, 256, 0, stream>>>(buf1, rs, csr_src, dinv, b1, W2, buf2, N);

    // ---- gather2 + linear3 fused -> hs3 ----
    gather_lin_kernel<<<G32, 256, 0, stream>>>(buf2, rs, csr_src, dinv, b2, W3, buf1, N);

    // ---- gather3 + pool partials (fp32, atomic flush) ----
    gather_pool_kernel<<<G32, 256, 0, stream>>>(buf1, rs, csr_src, dinv, b3, batch, gsum, N);

    // ---- tiny head: mean + MLP ----
    head_kernel<<<N_GRAPHS, 64, 0, stream>>>(gsum, batch, lin_W1, lin_b1, lin_W2, lin_b2,
                                             out, N, N_GRAPHS);
}